// Round 6
// baseline (302.878 us; speedup 1.0000x reference)
//
#include <hip/hip_runtime.h>

// SGFormer encoder layer, MI355X gfx950.
// fp32 I/O per reference dtypes; bf16 MFMA internally (error ~0.03 << 0.1 thr).
// R2: scatter-mean via CSR build + gather (was 1800us of fp32 atomics = 85%).
// R3/R4: static-max softmax flash attn (inputs bound |s|<~2, exp safe, split
//        partials additive), pre-transposed V, 32 rows/wave, K-split.
// R5: SPLITS=4, Q-frag prescale, merged LQKV gemm (128-tile), fused hist.
// R6: P staging rewrite: parity-interleaved Psx[row>>1][2c+(row&1)] ->
//     r-pairs pack to one dword (v_cvt_pk_bf16_f32 + ds_write_b32, 16/iter,
//     conflict-free banks) ; A-frag read = broadcast 32B window + v_perm
//     parity extract. Was 128 f2b + 32 ds_write_b16 (write-merge serialized).

#define N_NODES 4096
#define C_DIM   512
#define H_HEADS 8
#define D_HEAD  64
#define E_EDGES 131072

typedef unsigned short u16;
typedef unsigned int   u32;
typedef u16   u16x8  __attribute__((ext_vector_type(8)));
typedef u32   u32x4  __attribute__((ext_vector_type(4)));
typedef __bf16 bf16x8 __attribute__((ext_vector_type(8)));
typedef float  f32x4  __attribute__((ext_vector_type(4)));

__device__ __forceinline__ float b2f(u16 u) {
  unsigned int i = ((unsigned int)u) << 16;
  return __builtin_bit_cast(float, i);
}
__device__ __forceinline__ u16 f2b(float f) {
  unsigned int i = __builtin_bit_cast(unsigned int, f);
  i += 0x7fffu + ((i >> 16) & 1u);   // RNE
  return (u16)(i >> 16);
}
// pack two f32 -> bf16x2 in one dword (lo=a, hi=b)
__device__ __forceinline__ u32 pkbf(float a, float b) {
#if __has_builtin(__builtin_amdgcn_cvt_pk_bf16_f32)
  auto r = __builtin_amdgcn_cvt_pk_bf16_f32(a, b);
  return __builtin_bit_cast(u32, r);
#else
  return (u32)f2b(a) | ((u32)f2b(b) << 16);
#endif
}

// ---------------- fp32 -> bf16 batched convert (+ fused hist) ----------------
struct CvtArgs {
  const float* src[7];
  u16* dst[7];
  int n[7];
  const int* ei;
  int* deg;
};

__global__ __launch_bounds__(256) void cvt_multi(CvtArgs a) {
  const int t = blockIdx.y;
  if (t == 7) {                       // fused degree histogram
    if (blockIdx.x >= E_EDGES / 256) return;
    const int e = blockIdx.x * 256 + threadIdx.x;
    atomicAdd(&a.deg[a.ei[E_EDGES + e]], 1);
    return;
  }
  const int i = (blockIdx.x * 256 + threadIdx.x) * 8;
  if (i >= a.n[t]) return;
  const float* s = a.src[t] + i;
  f32x4 v0 = *(const f32x4*)s;
  f32x4 v1 = *(const f32x4*)(s + 4);
  u16x8 o;
  o[0]=f2b(v0[0]); o[1]=f2b(v0[1]); o[2]=f2b(v0[2]); o[3]=f2b(v0[3]);
  o[4]=f2b(v1[0]); o[5]=f2b(v1[1]); o[6]=f2b(v1[2]); o[7]=f2b(v1[3]);
  *(u16x8*)(a.dst[t] + i) = o;
}

// ---------------- 64x64 tile GEMM: out = A[M,K] * W[Nout,K]^T + bias --------
// EPI: 1 = f32 out, 3 = 0.5*local+0.5*v -> bf16
template<int EPI>
__global__ __launch_bounds__(256) void gemm_bt(
    const u16* __restrict__ A, const u16* __restrict__ W,
    const float* __restrict__ bias, void* __restrict__ outp,
    int M, int Nout, int K,
    const float* __restrict__ mloc)
{
  const int tid  = threadIdx.x;
  const int lane = tid & 63, wave = tid >> 6;
  const int quad = lane >> 4, l16 = lane & 15;
  const int wm = wave >> 1, wn = wave & 1;   // 2x2 wave grid, 32x32 per wave
  const int bm = blockIdx.x, bnb = blockIdx.y;

  __shared__ __align__(16) u16 As[64][72];   // +8 pad
  __shared__ __align__(16) u16 Ws[64][72];

  f32x4 acc[2][2] = {};

  const int srow = tid >> 2;           // 0..63
  const int scol = (tid & 3) << 4;     // 0,16,32,48
  const u16* ag = A + (size_t)(bm  * 64 + srow) * K + scol;
  const u16* wg = W + (size_t)(bnb * 64 + srow) * K + scol;

  for (int k0 = 0; k0 < K; k0 += 64) {
    u16x8 a0 = *(const u16x8*)(ag + k0);
    u16x8 a1 = *(const u16x8*)(ag + k0 + 8);
    u16x8 w0 = *(const u16x8*)(wg + k0);
    u16x8 w1 = *(const u16x8*)(wg + k0 + 8);
    __syncthreads();
    *(u16x8*)&As[srow][scol]     = a0;
    *(u16x8*)&As[srow][scol + 8] = a1;
    *(u16x8*)&Ws[srow][scol]     = w0;
    *(u16x8*)&Ws[srow][scol + 8] = w1;
    __syncthreads();
#pragma unroll
    for (int ks = 0; ks < 2; ++ks) {
      bf16x8 af[2], bf[2];
      af[0] = *(const bf16x8*)&As[wm * 32 +      l16][ks * 32 + quad * 8];
      af[1] = *(const bf16x8*)&As[wm * 32 + 16 + l16][ks * 32 + quad * 8];
      bf[0] = *(const bf16x8*)&Ws[wn * 32 +      l16][ks * 32 + quad * 8];
      bf[1] = *(const bf16x8*)&Ws[wn * 32 + 16 + l16][ks * 32 + quad * 8];
#pragma unroll
      for (int i = 0; i < 2; ++i)
#pragma unroll
        for (int j = 0; j < 2; ++j)
          acc[i][j] = __builtin_amdgcn_mfma_f32_16x16x32_bf16(af[i], bf[j], acc[i][j], 0, 0, 0);
    }
  }

#pragma unroll
  for (int i = 0; i < 2; ++i)
#pragma unroll
    for (int j = 0; j < 2; ++j) {
      const int col = bnb * 64 + wn * 32 + j * 16 + l16;
      const float bias_v = bias[col];
#pragma unroll
      for (int r = 0; r < 4; ++r) {
        const int row = bm * 64 + wm * 32 + i * 16 + quad * 4 + r;
        float v = acc[i][j][r] + bias_v;
        const size_t o = (size_t)row * Nout + col;
        if constexpr (EPI == 1) {
          ((float*)outp)[o] = v;
        } else {
          ((u16*)outp)[o] = f2b(0.5f * mloc[o] + 0.5f * v);
        }
      }
    }
}

// ---------------- 128x128 tile GEMM (m93-class) ----------------
// MODE 0: split LQKV epilogue (col<512 -> out0=local_h[.,512],
//         else out1=qkvb[.,1536] with bias1), bf16 out
// MODE 2: gelu -> bf16 out0 (stride Nout)
template<int MODE>
__global__ __launch_bounds__(256) void gemm128(
    const u16* __restrict__ A, const u16* __restrict__ W,
    const float* __restrict__ bias0, const float* __restrict__ bias1,
    u16* __restrict__ out0, u16* __restrict__ out1,
    int M, int Nout, int K)
{
  const int tid  = threadIdx.x;
  const int lane = tid & 63, wave = tid >> 6;
  const int quad = lane >> 4, l16 = lane & 15;
  const int wm = wave >> 1, wn = wave & 1;   // 2x2 wave grid, 64x64 per wave
  const int bm = blockIdx.x, bnb = blockIdx.y;

  __shared__ __align__(16) u16 As[128][72];
  __shared__ __align__(16) u16 Ws[128][72];

  f32x4 acc[4][4] = {};

  const int srow = tid >> 1;            // 0..127
  const int scol = (tid & 1) * 32;      // 0 or 32
  const u16* ag = A + (size_t)(bm  * 128 + srow) * K + scol;
  const u16* wg = W + (size_t)(bnb * 128 + srow) * K + scol;

  for (int k0 = 0; k0 < K; k0 += 64) {
    u16x8 a0 = *(const u16x8*)(ag + k0);
    u16x8 a1 = *(const u16x8*)(ag + k0 + 8);
    u16x8 a2 = *(const u16x8*)(ag + k0 + 16);
    u16x8 a3 = *(const u16x8*)(ag + k0 + 24);
    u16x8 w0 = *(const u16x8*)(wg + k0);
    u16x8 w1 = *(const u16x8*)(wg + k0 + 8);
    u16x8 w2 = *(const u16x8*)(wg + k0 + 16);
    u16x8 w3 = *(const u16x8*)(wg + k0 + 24);
    __syncthreads();
    *(u16x8*)&As[srow][scol]      = a0;
    *(u16x8*)&As[srow][scol + 8]  = a1;
    *(u16x8*)&As[srow][scol + 16] = a2;
    *(u16x8*)&As[srow][scol + 24] = a3;
    *(u16x8*)&Ws[srow][scol]      = w0;
    *(u16x8*)&Ws[srow][scol + 8]  = w1;
    *(u16x8*)&Ws[srow][scol + 16] = w2;
    *(u16x8*)&Ws[srow][scol + 24] = w3;
    __syncthreads();
#pragma unroll
    for (int ks = 0; ks < 2; ++ks) {
      bf16x8 af[4], bf[4];
#pragma unroll
      for (int am = 0; am < 4; ++am)
        af[am] = *(const bf16x8*)&As[wm * 64 + am * 16 + l16][ks * 32 + quad * 8];
#pragma unroll
      for (int bn = 0; bn < 4; ++bn)
        bf[bn] = *(const bf16x8*)&Ws[wn * 64 + bn * 16 + l16][ks * 32 + quad * 8];
#pragma unroll
      for (int am = 0; am < 4; ++am)
#pragma unroll
        for (int bn = 0; bn < 4; ++bn)
          acc[am][bn] = __builtin_amdgcn_mfma_f32_16x16x32_bf16(af[am], bf[bn], acc[am][bn], 0, 0, 0);
    }
  }

#pragma unroll
  for (int am = 0; am < 4; ++am)
#pragma unroll
    for (int bn = 0; bn < 4; ++bn) {
      const int col = bnb * 128 + wn * 64 + bn * 16 + l16;
      float bias_v;
      if constexpr (MODE == 0) bias_v = (col < 512) ? bias0[col] : bias1[col - 512];
      else                     bias_v = bias0[col];
#pragma unroll
      for (int r = 0; r < 4; ++r) {
        const int row = bm * 128 + wm * 64 + am * 16 + quad * 4 + r;
        float v = acc[am][bn][r] + bias_v;
        if constexpr (MODE == 0) {
          if (col < 512) out0[(size_t)row * 512 + col] = f2b(v);
          else           out1[(size_t)row * 1536 + (col - 512)] = f2b(v);
        } else {
          float gl = 0.5f * v * (1.0f + erff(v * 0.70710678118654752f));
          out0[(size_t)row * Nout + col] = f2b(gl);
        }
      }
    }
}

// ---------------- CSR build (by destination) ----------------
__global__ __launch_bounds__(256) void scan_kernel(
    const int* __restrict__ deg, int* __restrict__ off, int* __restrict__ cursor)
{
  __shared__ int part[256];
  const int t = threadIdx.x;
  int v[16];
  int s = 0;
#pragma unroll
  for (int i = 0; i < 16; ++i) { v[i] = deg[t * 16 + i]; s += v[i]; }
  part[t] = s;
  __syncthreads();
  for (int d = 1; d < 256; d <<= 1) {
    int val = (t >= d) ? part[t - d] : 0;
    __syncthreads();
    if (t >= d) part[t] += val;
    __syncthreads();
  }
  int prefix = (t == 0) ? 0 : part[t - 1];
#pragma unroll
  for (int i = 0; i < 16; ++i) {
    off[t * 16 + i] = prefix;
    cursor[t * 16 + i] = prefix;
    prefix += v[i];
  }
  if (t == 255) off[4096] = prefix;
}

__global__ __launch_bounds__(256) void fill_kernel(
    const int* __restrict__ ei, int* __restrict__ cursor, int* __restrict__ csr)
{
  const int e = blockIdx.x * 256 + threadIdx.x;
  const int s = ei[e];
  const int d = ei[E_EDGES + e];
  const int p = atomicAdd(&cursor[d], 1);
  csr[p] = s;
}

// gather-mean: one wave per dst node; coalesced 1KB row reads (L2-resident)
__global__ __launch_bounds__(256) void gather_kernel(
    const int* __restrict__ off, const int* __restrict__ csr,
    const u16* __restrict__ lh, float* __restrict__ lo)
{
  const int wave = threadIdx.x >> 6, lane = threadIdx.x & 63;
  const int n = blockIdx.x * 4 + wave;
  const int j0 = off[n], j1 = off[n + 1];
  float acc[8] = {};
  for (int j = j0; j < j1; ++j) {
    const int s = csr[j];
    const u16x8 v = *(const u16x8*)(lh + (size_t)s * C_DIM + lane * 8);
#pragma unroll
    for (int i = 0; i < 8; ++i) acc[i] += b2f(v[i]);
  }
  const float inv = 1.0f / fmaxf((float)(j1 - j0), 1.0f);
  f32x4 o0, o1;
#pragma unroll
  for (int i = 0; i < 4; ++i) { o0[i] = acc[i] * inv; o1[i] = acc[4 + i] * inv; }
  float* op = lo + (size_t)n * C_DIM + lane * 8;
  *(f32x4*)op = o0;
  *(f32x4*)(op + 4) = o1;
}

// ---------------- V transpose pack: vt[h][d][m] = V[m][h][d] ----------------
__global__ __launch_bounds__(256) void vtrans_kernel(
    const u16* __restrict__ qkv, u16* __restrict__ vt)
{
  const int tid = threadIdx.x;
  const int d = tid & 63, mg = tid >> 6;   // mg 0..3
  const int h = blockIdx.y, mt = blockIdx.x;
  const int m0 = mt * 64 + mg * 16;
  u16 buf[16];
#pragma unroll
  for (int i = 0; i < 16; ++i)
    buf[i] = qkv[(size_t)(m0 + i) * 1536 + 1024 + h * 64 + d];
  u16x8 w0, w1;
#pragma unroll
  for (int i = 0; i < 8; ++i) { w0[i] = buf[i]; w1[i] = buf[8 + i]; }
  u16* op = vt + (size_t)(h * 64 + d) * N_NODES + m0;
  *(u16x8*)op = w0;
  *(u16x8*)(op + 8) = w1;
}

// ---------------- flash attention (static max, K-split) ----------------
// grid (32 row-tiles of 128, 8 heads, SPLITS). Wave owns 32 rows (2 frags).
// Q frags pre-scaled by log2(e)/8 so inner loop is exp2(s) directly.
// P staging: Psx[row>>1][2*col + (row&1)] — r-pairs pack into one dword.
template<int SPLITS>
__global__ __launch_bounds__(256) void attn_kernel(
    const u16* __restrict__ qkv, const u16* __restrict__ vt,
    float* __restrict__ opart, float* __restrict__ lpart)
{
  const int tid = threadIdx.x, wave = tid >> 6, lane = tid & 63;
  const int quad = lane >> 4, l16 = lane & 15;
  const int h = blockIdx.y, tile = blockIdx.x, split = blockIdx.z;

  __shared__ __align__(16) u16 Ks[64][72];     // K tile [m'][d]
  __shared__ __align__(16) u16 Vts[64][72];    // V^T tile [d][m']
  __shared__ __align__(16) u16 Psx[64][144];   // P parity-interleaved

  const float QSCALE = 0.18033688011112042f;  // log2(e)/8
  bf16x8 aq[2][2];
#pragma unroll
  for (int mb = 0; mb < 2; ++mb) {
    const int qrow = tile * 128 + wave * 32 + mb * 16 + l16;
    const u16* qp = qkv + (size_t)qrow * 1536 + h * 64 + quad * 8;
    u16x8 q0 = *(const u16x8*)qp;
    u16x8 q1 = *(const u16x8*)(qp + 32);
    u16x8 s0, s1;
#pragma unroll
    for (int i = 0; i < 8; ++i) {
      s0[i] = f2b(b2f(q0[i]) * QSCALE);
      s1[i] = f2b(b2f(q1[i]) * QSCALE);
    }
    aq[mb][0] = __builtin_bit_cast(bf16x8, s0);
    aq[mb][1] = __builtin_bit_cast(bf16x8, s1);
  }

  f32x4 O[2][4] = {};
  float lsum[2][4] = {};   // per-lane partial row sums

  const int srow = tid >> 2;          // staging row 0..63
  const int scol = (tid & 3) << 4;    // staging col offset
  const u32 psel = (l16 & 1) ? 0x07060302u : 0x05040100u;  // parity extract

  const int mt1 = (split + 1) * (64 / SPLITS);
  for (int mt = split * (64 / SPLITS); mt < mt1; ++mt) {
    const u16* kp = qkv + (size_t)(mt * 64 + srow) * 1536 + 512 + h * 64 + scol;
    const u16* vp = vt + (size_t)(h * 64 + srow) * N_NODES + mt * 64 + scol;
    u16x8 k0 = *(const u16x8*)kp;
    u16x8 k1 = *(const u16x8*)(kp + 8);
    u16x8 v0 = *(const u16x8*)vp;
    u16x8 v1 = *(const u16x8*)(vp + 8);
    __syncthreads();                  // prior iter's Ks/Vts reads complete
    *(u16x8*)&Ks[srow][scol]      = k0;
    *(u16x8*)&Ks[srow][scol + 8]  = k1;
    *(u16x8*)&Vts[srow][scol]     = v0;
    *(u16x8*)&Vts[srow][scol + 8] = v1;
    __syncthreads();

    // S = (cQ) K^T
    f32x4 s[2][4] = {};
#pragma unroll
    for (int ks = 0; ks < 2; ++ks) {
      bf16x8 bk[4];
#pragma unroll
      for (int jn = 0; jn < 4; ++jn)
        bk[jn] = *(const bf16x8*)&Ks[jn * 16 + l16][ks * 32 + quad * 8];
#pragma unroll
      for (int mb = 0; mb < 2; ++mb)
#pragma unroll
        for (int jn = 0; jn < 4; ++jn)
          s[mb][jn] = __builtin_amdgcn_mfma_f32_16x16x32_bf16(aq[mb][ks], bk[jn], s[mb][jn], 0, 0, 0);
    }

    // p = exp2(s); pack r-pairs -> one dword; conflict-free b32 LDS writes
#pragma unroll
    for (int mb = 0; mb < 2; ++mb) {
      const int prow = wave * 16 + mb * 8 + quad * 2;
#pragma unroll
      for (int jn = 0; jn < 4; ++jn) {
        float p0 = __builtin_amdgcn_exp2f(s[mb][jn][0]);
        float p1 = __builtin_amdgcn_exp2f(s[mb][jn][1]);
        float p2 = __builtin_amdgcn_exp2f(s[mb][jn][2]);
        float p3 = __builtin_amdgcn_exp2f(s[mb][jn][3]);
        lsum[mb][0] += p0; lsum[mb][1] += p1;
        lsum[mb][2] += p2; lsum[mb][3] += p3;
        *(u32*)&Psx[prow    ][(jn * 16 + l16) * 2] = pkbf(p0, p1);
        *(u32*)&Psx[prow + 1][(jn * 16 + l16) * 2] = pkbf(p2, p3);
      }
    }
    // no barrier: Psx rows are wave-private; lgkmcnt ordering handles RAW

    // O += P V   (A-frag: broadcast 32B window + v_perm parity extract)
#pragma unroll
    for (int ks = 0; ks < 2; ++ks) {
      bf16x8 bv[4];
#pragma unroll
      for (int jd = 0; jd < 4; ++jd)
        bv[jd] = *(const bf16x8*)&Vts[jd * 16 + l16][ks * 32 + quad * 8];
#pragma unroll
      for (int mb = 0; mb < 2; ++mb) {
        const int pr = wave * 16 + mb * 8 + (l16 >> 1);
        const int pc = ks * 64 + quad * 16;
        u32x4 wa = *(const u32x4*)&Psx[pr][pc];
        u32x4 wb = *(const u32x4*)&Psx[pr][pc + 8];
        u32x4 ov;
        ov[0] = __builtin_amdgcn_perm(wa[1], wa[0], psel);
        ov[1] = __builtin_amdgcn_perm(wa[3], wa[2], psel);
        ov[2] = __builtin_amdgcn_perm(wb[1], wb[0], psel);
        ov[3] = __builtin_amdgcn_perm(wb[3], wb[2], psel);
        bf16x8 ap = __builtin_bit_cast(bf16x8, ov);
#pragma unroll
        for (int jd = 0; jd < 4; ++jd)
          O[mb][jd] = __builtin_amdgcn_mfma_f32_16x16x32_bf16(ap, bv[jd], O[mb][jd], 0, 0, 0);
      }
    }
  }

  // one-time 16-lane reduce of row-sum partials
#pragma unroll
  for (int mb = 0; mb < 2; ++mb)
#pragma unroll
    for (int r = 0; r < 4; ++r)
#pragma unroll
      for (int off = 1; off < 16; off <<= 1)
        lsum[mb][r] += __shfl_xor(lsum[mb][r], off);

  // write unnormalized partials
#pragma unroll
  for (int mb = 0; mb < 2; ++mb)
#pragma unroll
    for (int r = 0; r < 4; ++r) {
      const int row = tile * 128 + wave * 32 + mb * 16 + quad * 4 + r;
      float* orow = opart + ((size_t)split * N_NODES + row) * C_DIM + h * 64;
#pragma unroll
      for (int jd = 0; jd < 4; ++jd)
        orow[jd * 16 + l16] = O[mb][jd][r];
      if (l16 == 0)
        lpart[((size_t)split * N_NODES + row) * H_HEADS + h] = lsum[mb][r];
    }
}

template<int SPLITS>
__global__ __launch_bounds__(256) void attn_combine(
    const float* __restrict__ opart, const float* __restrict__ lpart,
    u16* __restrict__ ctx)
{
  const size_t base = (size_t)(blockIdx.x * 256 + threadIdx.x) * 8;
  const int row = (int)(base >> 9);
  const int h = (int)((base & 511) >> 6);
  float l = 0.0f;
#pragma unroll
  for (int s = 0; s < SPLITS; ++s)
    l += lpart[(size_t)s * N_NODES * H_HEADS + (size_t)row * H_HEADS + h];
  const float inv = 1.0f / l;
  float o[8] = {};
#pragma unroll
  for (int s = 0; s < SPLITS; ++s) {
    const float* op = opart + (size_t)s * N_NODES * C_DIM + base;
    f32x4 p0 = *(const f32x4*)op;
    f32x4 p1 = *(const f32x4*)(op + 4);
#pragma unroll
    for (int i = 0; i < 4; ++i) { o[i] += p0[i]; o[4 + i] += p1[i]; }
  }
  u16x8 ob;
#pragma unroll
  for (int i = 0; i < 8; ++i) ob[i] = f2b(o[i] * inv);
  *(u16x8*)(ctx + base) = ob;
}

// ---------------- LayerNorms (one wave per row) ----------------
__global__ __launch_bounds__(256) void ln1_kernel(
    const float* __restrict__ x, const float* __restrict__ pr,
    const float* __restrict__ g, const float* __restrict__ b,
    u16* __restrict__ hb, float* __restrict__ hf)
{
  const int wave = threadIdx.x >> 6, lane = threadIdx.x & 63;
  const int row = blockIdx.x * 4 + wave;
  const int c0 = lane * 8;
  const size_t base = (size_t)row * C_DIM + c0;
  f32x4 x0 = *(const f32x4*)(x + base);
  f32x4 x1 = *(const f32x4*)(x + base + 4);
  f32x4 p0 = *(const f32x4*)(pr + base);
  f32x4 p1 = *(const f32x4*)(pr + base + 4);
  float v[8];
#pragma unroll
  for (int i = 0; i < 4; ++i) { v[i] = x0[i] + p0[i]; v[4 + i] = x1[i] + p1[i]; }
  float sum = 0, sq = 0;
#pragma unroll
  for (int i = 0; i < 8; ++i) { sum += v[i]; sq += v[i] * v[i]; }
  for (int off = 1; off < 64; off <<= 1) { sum += __shfl_xor(sum, off); sq += __shfl_xor(sq, off); }
  const float mean = sum * (1.0f / C_DIM);
  const float var  = sq * (1.0f / C_DIM) - mean * mean;
  const float rstd = rsqrtf(var + 1e-5f);
  f32x4 g0 = *(const f32x4*)(g + c0), g1 = *(const f32x4*)(g + c0 + 4);
  f32x4 b0 = *(const f32x4*)(b + c0), b1 = *(const f32x4*)(b + c0 + 4);
  u16x8 ob; f32x4 h0, h1;
#pragma unroll
  for (int i = 0; i < 4; ++i) {
    float hv0 = (v[i]     - mean) * rstd * g0[i] + b0[i];
    float hv1 = (v[4 + i] - mean) * rstd * g1[i] + b1[i];
    h0[i] = hv0; h1[i] = hv1;
    ob[i] = f2b(hv0); ob[4 + i] = f2b(hv1);
  }
  *(u16x8*)(hb + base) = ob;
  *(f32x4*)(hf + base) = h0;
  *(f32x4*)(hf + base + 4) = h1;
}

__global__ __launch_bounds__(256) void ln2_kernel(
    const float* __restrict__ a, const float* __restrict__ c,
    const float* __restrict__ g, const float* __restrict__ b,
    float* __restrict__ out)
{
  const int wave = threadIdx.x >> 6, lane = threadIdx.x & 63;
  const int row = blockIdx.x * 4 + wave;
  const int c0 = lane * 8;
  const size_t base = (size_t)row * C_DIM + c0;
  f32x4 a0 = *(const f32x4*)(a + base), a1 = *(const f32x4*)(a + base + 4);
  f32x4 c0v = *(const f32x4*)(c + base), c1v = *(const f32x4*)(c + base + 4);
  float v[8];
#pragma unroll
  for (int i = 0; i < 4; ++i) { v[i] = a0[i] + c0v[i]; v[4 + i] = a1[i] + c1v[i]; }
  float sum = 0, sq = 0;
#pragma unroll
  for (int i = 0; i < 8; ++i) { sum += v[i]; sq += v[i] * v[i]; }
  for (int off = 1; off < 64; off <<= 1) { sum += __shfl_xor(sum, off); sq += __shfl_xor(sq, off); }
  const float mean = sum * (1.0f / C_DIM);
  const float var  = sq * (1.0f / C_DIM) - mean * mean;
  const float rstd = rsqrtf(var + 1e-5f);
  f32x4 g0 = *(const f32x4*)(g + c0), g1 = *(const f32x4*)(g + c0 + 4);
  f32x4 b0 = *(const f32x4*)(b + c0), b1 = *(const f32x4*)(b + c0 + 4);
  f32x4 h0, h1;
#pragma unroll
  for (int i = 0; i < 4; ++i) {
    h0[i] = (v[i]     - mean) * rstd * g0[i] + b0[i];
    h1[i] = (v[4 + i] - mean) * rstd * g1[i] + b1[i];
  }
  *(f32x4*)(out + base) = h0;
  *(f32x4*)(out + base + 4) = h1;
}

// ---------------- launch ----------------
extern "C" void kernel_launch(void* const* d_in, const int* in_sizes, int n_in,
                              void* d_out, int out_size, void* d_ws, size_t ws_size,
                              hipStream_t stream) {
  const float* x          = (const float*)d_in[0];
  const int*   ei         = (const int*)d_in[1];
  const float* local_w    = (const float*)d_in[2];
  const float* local_b    = (const float*)d_in[3];
  const float* in_proj_w  = (const float*)d_in[4];
  const float* in_proj_b  = (const float*)d_in[5];
  const float* attn_out_w = (const float*)d_in[6];
  const float* attn_out_b = (const float*)d_in[7];
  const float* output_w   = (const float*)d_in[8];
  const float* output_b   = (const float*)d_in[9];
  const float* n1g = (const float*)d_in[10];
  const float* n1b = (const float*)d_in[11];
  const float* n2g = (const float*)d_in[12];
  const float* n2b = (const float*)d_in[13];
  const float* ffn_w1 = (const float*)d_in[14];
  const float* ffn_b1 = (const float*)d_in[15];
  const float* ffn_w2 = (const float*)d_in[16];
  const float* ffn_b2 = (const float*)d_in[17];
  float* out = (float*)d_out;

  char* ws = (char*)d_ws;
  size_t o = 0;
  float* local_out = (float*)(ws + o); o += (size_t)N_NODES * C_DIM * 4;  // 8 MB
  int* deg    = (int*)(ws + o); o += (N_NODES) * 4;
  int* off    = (int*)(ws + o); o += (N_NODES + 16) * 4;
  int* cursor = (int*)(ws + o); o += (N_NODES) * 4;
  int* csr    = (int*)(ws + o); o += (size_t)E_EDGES * 4;
  u16* xb   = (u16*)(ws + o); o += (size_t)N_NODES * C_DIM * 2;           // 4 MB
  u16* wbLQ = (u16*)(ws + o); o += (size_t)4 * C_DIM * C_DIM * 2;         // 2 MB
  u16* wbA  = (u16*)(ws + o); o += (size_t)C_DIM * C_DIM * 2;
  u16* wbO  = (u16*)(ws + o); o += (size_t)C_DIM * C_DIM * 2;
  u16* wbF1 = (u16*)(ws + o); o += (size_t)2 * C_DIM * C_DIM * 2;
  u16* wbF2 = (u16*)(ws + o); o += (size_t)2 * C_DIM * C_DIM * 2;
  u16* local_h   = (u16*)(ws + o); o += (size_t)N_NODES * C_DIM * 2;
  u16* qkvb      = (u16*)(ws + o); o += (size_t)N_NODES * 3 * C_DIM * 2;  // 12 MB
  u16* ctxb      = (u16*)(ws + o); o += (size_t)N_NODES * C_DIM * 2;
  u16* mixed     = (u16*)(ws + o); o += (size_t)N_NODES * C_DIM * 2;
  u16* hidden_bf = (u16*)(ws + o); o += (size_t)N_NODES * C_DIM * 2;      // 4 MB
  float* hidden_f = (float*)(ws + o); o += (size_t)N_NODES * C_DIM * 4;   // 8 MB
  u16* ff1       = (u16*)(ws + o); o += (size_t)N_NODES * 2 * C_DIM * 2;  // 8 MB
  // aliases (dead ranges reused):
  float* proj  = (float*)qkvb;       // qkv dead after attn; proj 8 MB <= 12 MB
  float* ff2   = (float*)local_out;  // local_out dead after mix-epilogue gemm
  u16*   vt    = xb;                 // xb dead after LQKV gemm; 4 MB
  // SPLITS=4 scratch (32.5 MB) goes past ff1 if workspace allows
  float* opart4 = (float*)(ws + o);
  float* lpart4 = (float*)(ws + o + (size_t)4 * N_NODES * C_DIM * 4);
  const size_t need4 = o + (size_t)4 * N_NODES * C_DIM * 4 + (size_t)4 * N_NODES * H_HEADS * 4;
  const bool use4 = (ws_size >= need4);
  // SPLITS=2 fallback: inside hidden_bf..ff1 region (16.25 MB <= 20 MB)
  float* opart2 = (float*)hidden_bf;
  float* lpart2 = opart2 + (size_t)2 * N_NODES * C_DIM;

  (void)hipMemsetAsync(deg, 0, N_NODES * 4, stream);

  // fp32 -> bf16 conversions (x + weights) + fused degree histogram
  CvtArgs ca;
  ca.src[0] = x;          ca.dst[0] = xb;   ca.n[0] = N_NODES * C_DIM;
  ca.src[1] = local_w;    ca.dst[1] = wbLQ;                  ca.n[1] = C_DIM * C_DIM;
  ca.src[2] = in_proj_w;  ca.dst[2] = wbLQ + C_DIM * C_DIM;  ca.n[2] = 3 * C_DIM * C_DIM;
  ca.src[3] = attn_out_w; ca.dst[3] = wbA;  ca.n[3] = C_DIM * C_DIM;
  ca.src[4] = output_w;   ca.dst[4] = wbO;  ca.n[4] = C_DIM * C_DIM;
  ca.src[5] = ffn_w1;     ca.dst[5] = wbF1; ca.n[5] = 2 * C_DIM * C_DIM;
  ca.src[6] = ffn_w2;     ca.dst[6] = wbF2; ca.n[6] = 2 * C_DIM * C_DIM;
  ca.ei = ei; ca.deg = deg;
  cvt_multi<<<dim3(N_NODES * C_DIM / 2048, 8), 256, 0, stream>>>(ca);

  // CSR build
  scan_kernel<<<1, 256, 0, stream>>>(deg, off, cursor);
  fill_kernel<<<E_EDGES / 256, 256, 0, stream>>>(ei, cursor, csr);

  // merged local+qkv GEMM: [local_h | qkvb] = xb @ [local_w; in_proj_w]^T
  gemm128<0><<<dim3(32, 16), 256, 0, stream>>>(xb, wbLQ, local_b, in_proj_b,
      local_h, qkvb, N_NODES, 4 * C_DIM, C_DIM);
  gather_kernel<<<N_NODES / 4, 256, 0, stream>>>(off, csr, local_h, local_out);

  // global branch
  vtrans_kernel<<<dim3(64, 8), 256, 0, stream>>>(qkvb, vt);   // xb dead now
  if (use4) {
    attn_kernel<4><<<dim3(32, 8, 4), 256, 0, stream>>>(qkvb, vt, opart4, lpart4);
    attn_combine<4><<<N_NODES * C_DIM / 2048, 256, 0, stream>>>(opart4, lpart4, ctxb);
  } else {
    attn_kernel<2><<<dim3(32, 8, 2), 256, 0, stream>>>(qkvb, vt, opart2, lpart2);
    attn_combine<2><<<N_NODES * C_DIM / 2048, 256, 0, stream>>>(opart2, lpart2, ctxb);
  }

  // mixed = 0.5*local_out + 0.5*(ctx @ attn_out_w^T + b)
  gemm_bt<3><<<dim3(64, 8), 256, 0, stream>>>(ctxb, wbA, attn_out_b, mixed,
      N_NODES, C_DIM, C_DIM, local_out);

  // proj = mixed @ output_w^T + b ; hidden = LN(x + proj)
  gemm_bt<1><<<dim3(64, 8), 256, 0, stream>>>(mixed, wbO, output_b, proj,
      N_NODES, C_DIM, C_DIM, nullptr);
  ln1_kernel<<<N_NODES / 4, 256, 0, stream>>>(x, proj, n1g, n1b, hidden_bf, hidden_f);

  // FFN
  gemm128<2><<<dim3(32, 8), 256, 0, stream>>>(hidden_bf, wbF1, ffn_b1, nullptr,
      ff1, nullptr, N_NODES, 2 * C_DIM, C_DIM);
  gemm_bt<1><<<dim3(64, 8), 256, 0, stream>>>(ff1, wbF2, ffn_b2, ff2,
      N_NODES, C_DIM, 2 * C_DIM, nullptr);
  ln2_kernel<<<N_NODES / 4, 256, 0, stream>>>(hidden_f, ff2, n2g, n2b, out);
}

// Round 7
// 295.845 us; speedup vs baseline: 1.0238x; 1.0238x over previous
//
#include <hip/hip_runtime.h>

// SGFormer encoder layer, MI355X gfx950.
// fp32 I/O per reference dtypes; bf16 MFMA internally (error ~0.03 << 0.1 thr).
// R2: scatter-mean via CSR build + gather (was 1800us of fp32 atomics = 85%).
// R3/R4: static-max softmax flash attn (inputs bound |s|<~2, exp safe, split
//        partials additive), pre-transposed V, 32 rows/wave, K-split.
// R5: SPLITS=4, Q-frag prescale, merged LQKV gemm (128-tile), fused hist.
// R6 REGRESSED (parity-interleaved P + v_perm: fallback pack path + VGPR 72
//    killed occupancy; conflicts rose). R7: revert to R5 P-staging, with
//    round-half-up bf16 P writes (2 VALU vs ~4 for RNE; bias << bf16 budget).

#define N_NODES 4096
#define C_DIM   512
#define H_HEADS 8
#define D_HEAD  64
#define E_EDGES 131072

typedef unsigned short u16;
typedef unsigned int   u32;
typedef u16   u16x8  __attribute__((ext_vector_type(8)));
typedef __bf16 bf16x8 __attribute__((ext_vector_type(8)));
typedef float  f32x4  __attribute__((ext_vector_type(4)));

__device__ __forceinline__ float b2f(u16 u) {
  unsigned int i = ((unsigned int)u) << 16;
  return __builtin_bit_cast(float, i);
}
__device__ __forceinline__ u16 f2b(float f) {
  unsigned int i = __builtin_bit_cast(unsigned int, f);
  i += 0x7fffu + ((i >> 16) & 1u);   // RNE
  return (u16)(i >> 16);
}
__device__ __forceinline__ u16 f2b_up(float f) {   // round-half-up (cheaper)
  unsigned int i = __builtin_bit_cast(unsigned int, f);
  return (u16)((i + 0x8000u) >> 16);
}

// ---------------- fp32 -> bf16 batched convert (+ fused hist) ----------------
struct CvtArgs {
  const float* src[7];
  u16* dst[7];
  int n[7];
  const int* ei;
  int* deg;
};

__global__ __launch_bounds__(256) void cvt_multi(CvtArgs a) {
  const int t = blockIdx.y;
  if (t == 7) {                       // fused degree histogram
    if (blockIdx.x >= E_EDGES / 256) return;
    const int e = blockIdx.x * 256 + threadIdx.x;
    atomicAdd(&a.deg[a.ei[E_EDGES + e]], 1);
    return;
  }
  const int i = (blockIdx.x * 256 + threadIdx.x) * 8;
  if (i >= a.n[t]) return;
  const float* s = a.src[t] + i;
  f32x4 v0 = *(const f32x4*)s;
  f32x4 v1 = *(const f32x4*)(s + 4);
  u16x8 o;
  o[0]=f2b(v0[0]); o[1]=f2b(v0[1]); o[2]=f2b(v0[2]); o[3]=f2b(v0[3]);
  o[4]=f2b(v1[0]); o[5]=f2b(v1[1]); o[6]=f2b(v1[2]); o[7]=f2b(v1[3]);
  *(u16x8*)(a.dst[t] + i) = o;
}

// ---------------- 64x64 tile GEMM: out = A[M,K] * W[Nout,K]^T + bias --------
// EPI: 1 = f32 out, 3 = 0.5*local+0.5*v -> bf16
template<int EPI>
__global__ __launch_bounds__(256) void gemm_bt(
    const u16* __restrict__ A, const u16* __restrict__ W,
    const float* __restrict__ bias, void* __restrict__ outp,
    int M, int Nout, int K,
    const float* __restrict__ mloc)
{
  const int tid  = threadIdx.x;
  const int lane = tid & 63, wave = tid >> 6;
  const int quad = lane >> 4, l16 = lane & 15;
  const int wm = wave >> 1, wn = wave & 1;   // 2x2 wave grid, 32x32 per wave
  const int bm = blockIdx.x, bnb = blockIdx.y;

  __shared__ __align__(16) u16 As[64][72];   // +8 pad
  __shared__ __align__(16) u16 Ws[64][72];

  f32x4 acc[2][2] = {};

  const int srow = tid >> 2;           // 0..63
  const int scol = (tid & 3) << 4;     // 0,16,32,48
  const u16* ag = A + (size_t)(bm  * 64 + srow) * K + scol;
  const u16* wg = W + (size_t)(bnb * 64 + srow) * K + scol;

  for (int k0 = 0; k0 < K; k0 += 64) {
    u16x8 a0 = *(const u16x8*)(ag + k0);
    u16x8 a1 = *(const u16x8*)(ag + k0 + 8);
    u16x8 w0 = *(const u16x8*)(wg + k0);
    u16x8 w1 = *(const u16x8*)(wg + k0 + 8);
    __syncthreads();
    *(u16x8*)&As[srow][scol]     = a0;
    *(u16x8*)&As[srow][scol + 8] = a1;
    *(u16x8*)&Ws[srow][scol]     = w0;
    *(u16x8*)&Ws[srow][scol + 8] = w1;
    __syncthreads();
#pragma unroll
    for (int ks = 0; ks < 2; ++ks) {
      bf16x8 af[2], bf[2];
      af[0] = *(const bf16x8*)&As[wm * 32 +      l16][ks * 32 + quad * 8];
      af[1] = *(const bf16x8*)&As[wm * 32 + 16 + l16][ks * 32 + quad * 8];
      bf[0] = *(const bf16x8*)&Ws[wn * 32 +      l16][ks * 32 + quad * 8];
      bf[1] = *(const bf16x8*)&Ws[wn * 32 + 16 + l16][ks * 32 + quad * 8];
#pragma unroll
      for (int i = 0; i < 2; ++i)
#pragma unroll
        for (int j = 0; j < 2; ++j)
          acc[i][j] = __builtin_amdgcn_mfma_f32_16x16x32_bf16(af[i], bf[j], acc[i][j], 0, 0, 0);
    }
  }

#pragma unroll
  for (int i = 0; i < 2; ++i)
#pragma unroll
    for (int j = 0; j < 2; ++j) {
      const int col = bnb * 64 + wn * 32 + j * 16 + l16;
      const float bias_v = bias[col];
#pragma unroll
      for (int r = 0; r < 4; ++r) {
        const int row = bm * 64 + wm * 32 + i * 16 + quad * 4 + r;
        float v = acc[i][j][r] + bias_v;
        const size_t o = (size_t)row * Nout + col;
        if constexpr (EPI == 1) {
          ((float*)outp)[o] = v;
        } else {
          ((u16*)outp)[o] = f2b(0.5f * mloc[o] + 0.5f * v);
        }
      }
    }
}

// ---------------- 128x128 tile GEMM (m93-class) ----------------
// MODE 0: split LQKV epilogue (col<512 -> out0=local_h[.,512],
//         else out1=qkvb[.,1536] with bias1), bf16 out
// MODE 2: gelu -> bf16 out0 (stride Nout)
template<int MODE>
__global__ __launch_bounds__(256) void gemm128(
    const u16* __restrict__ A, const u16* __restrict__ W,
    const float* __restrict__ bias0, const float* __restrict__ bias1,
    u16* __restrict__ out0, u16* __restrict__ out1,
    int M, int Nout, int K)
{
  const int tid  = threadIdx.x;
  const int lane = tid & 63, wave = tid >> 6;
  const int quad = lane >> 4, l16 = lane & 15;
  const int wm = wave >> 1, wn = wave & 1;   // 2x2 wave grid, 64x64 per wave
  const int bm = blockIdx.x, bnb = blockIdx.y;

  __shared__ __align__(16) u16 As[128][72];
  __shared__ __align__(16) u16 Ws[128][72];

  f32x4 acc[4][4] = {};

  const int srow = tid >> 1;            // 0..127
  const int scol = (tid & 1) * 32;      // 0 or 32
  const u16* ag = A + (size_t)(bm  * 128 + srow) * K + scol;
  const u16* wg = W + (size_t)(bnb * 128 + srow) * K + scol;

  for (int k0 = 0; k0 < K; k0 += 64) {
    u16x8 a0 = *(const u16x8*)(ag + k0);
    u16x8 a1 = *(const u16x8*)(ag + k0 + 8);
    u16x8 a2 = *(const u16x8*)(ag + k0 + 16);
    u16x8 a3 = *(const u16x8*)(ag + k0 + 24);
    u16x8 w0 = *(const u16x8*)(wg + k0);
    u16x8 w1 = *(const u16x8*)(wg + k0 + 8);
    u16x8 w2 = *(const u16x8*)(wg + k0 + 16);
    u16x8 w3 = *(const u16x8*)(wg + k0 + 24);
    __syncthreads();
    *(u16x8*)&As[srow][scol]      = a0;
    *(u16x8*)&As[srow][scol + 8]  = a1;
    *(u16x8*)&As[srow][scol + 16] = a2;
    *(u16x8*)&As[srow][scol + 24] = a3;
    *(u16x8*)&Ws[srow][scol]      = w0;
    *(u16x8*)&Ws[srow][scol + 8]  = w1;
    *(u16x8*)&Ws[srow][scol + 16] = w2;
    *(u16x8*)&Ws[srow][scol + 24] = w3;
    __syncthreads();
#pragma unroll
    for (int ks = 0; ks < 2; ++ks) {
      bf16x8 af[4], bf[4];
#pragma unroll
      for (int am = 0; am < 4; ++am)
        af[am] = *(const bf16x8*)&As[wm * 64 + am * 16 + l16][ks * 32 + quad * 8];
#pragma unroll
      for (int bn = 0; bn < 4; ++bn)
        bf[bn] = *(const bf16x8*)&Ws[wn * 64 + bn * 16 + l16][ks * 32 + quad * 8];
#pragma unroll
      for (int am = 0; am < 4; ++am)
#pragma unroll
        for (int bn = 0; bn < 4; ++bn)
          acc[am][bn] = __builtin_amdgcn_mfma_f32_16x16x32_bf16(af[am], bf[bn], acc[am][bn], 0, 0, 0);
    }
  }

#pragma unroll
  for (int am = 0; am < 4; ++am)
#pragma unroll
    for (int bn = 0; bn < 4; ++bn) {
      const int col = bnb * 128 + wn * 64 + bn * 16 + l16;
      float bias_v;
      if constexpr (MODE == 0) bias_v = (col < 512) ? bias0[col] : bias1[col - 512];
      else                     bias_v = bias0[col];
#pragma unroll
      for (int r = 0; r < 4; ++r) {
        const int row = bm * 128 + wm * 64 + am * 16 + quad * 4 + r;
        float v = acc[am][bn][r] + bias_v;
        if constexpr (MODE == 0) {
          if (col < 512) out0[(size_t)row * 512 + col] = f2b(v);
          else           out1[(size_t)row * 1536 + (col - 512)] = f2b(v);
        } else {
          float gl = 0.5f * v * (1.0f + erff(v * 0.70710678118654752f));
          out0[(size_t)row * Nout + col] = f2b(gl);
        }
      }
    }
}

// ---------------- CSR build (by destination) ----------------
__global__ __launch_bounds__(256) void scan_kernel(
    const int* __restrict__ deg, int* __restrict__ off, int* __restrict__ cursor)
{
  __shared__ int part[256];
  const int t = threadIdx.x;
  int v[16];
  int s = 0;
#pragma unroll
  for (int i = 0; i < 16; ++i) { v[i] = deg[t * 16 + i]; s += v[i]; }
  part[t] = s;
  __syncthreads();
  for (int d = 1; d < 256; d <<= 1) {
    int val = (t >= d) ? part[t - d] : 0;
    __syncthreads();
    if (t >= d) part[t] += val;
    __syncthreads();
  }
  int prefix = (t == 0) ? 0 : part[t - 1];
#pragma unroll
  for (int i = 0; i < 16; ++i) {
    off[t * 16 + i] = prefix;
    cursor[t * 16 + i] = prefix;
    prefix += v[i];
  }
  if (t == 255) off[4096] = prefix;
}

__global__ __launch_bounds__(256) void fill_kernel(
    const int* __restrict__ ei, int* __restrict__ cursor, int* __restrict__ csr)
{
  const int e = blockIdx.x * 256 + threadIdx.x;
  const int s = ei[e];
  const int d = ei[E_EDGES + e];
  const int p = atomicAdd(&cursor[d], 1);
  csr[p] = s;
}

// gather-mean: one wave per dst node; coalesced 1KB row reads (L2-resident)
__global__ __launch_bounds__(256) void gather_kernel(
    const int* __restrict__ off, const int* __restrict__ csr,
    const u16* __restrict__ lh, float* __restrict__ lo)
{
  const int wave = threadIdx.x >> 6, lane = threadIdx.x & 63;
  const int n = blockIdx.x * 4 + wave;
  const int j0 = off[n], j1 = off[n + 1];
  float acc[8] = {};
  for (int j = j0; j < j1; ++j) {
    const int s = csr[j];
    const u16x8 v = *(const u16x8*)(lh + (size_t)s * C_DIM + lane * 8);
#pragma unroll
    for (int i = 0; i < 8; ++i) acc[i] += b2f(v[i]);
  }
  const float inv = 1.0f / fmaxf((float)(j1 - j0), 1.0f);
  f32x4 o0, o1;
#pragma unroll
  for (int i = 0; i < 4; ++i) { o0[i] = acc[i] * inv; o1[i] = acc[4 + i] * inv; }
  float* op = lo + (size_t)n * C_DIM + lane * 8;
  *(f32x4*)op = o0;
  *(f32x4*)(op + 4) = o1;
}

// ---------------- V transpose pack: vt[h][d][m] = V[m][h][d] ----------------
__global__ __launch_bounds__(256) void vtrans_kernel(
    const u16* __restrict__ qkv, u16* __restrict__ vt)
{
  const int tid = threadIdx.x;
  const int d = tid & 63, mg = tid >> 6;   // mg 0..3
  const int h = blockIdx.y, mt = blockIdx.x;
  const int m0 = mt * 64 + mg * 16;
  u16 buf[16];
#pragma unroll
  for (int i = 0; i < 16; ++i)
    buf[i] = qkv[(size_t)(m0 + i) * 1536 + 1024 + h * 64 + d];
  u16x8 w0, w1;
#pragma unroll
  for (int i = 0; i < 8; ++i) { w0[i] = buf[i]; w1[i] = buf[8 + i]; }
  u16* op = vt + (size_t)(h * 64 + d) * N_NODES + m0;
  *(u16x8*)op = w0;
  *(u16x8*)(op + 8) = w1;
}

// ---------------- flash attention (static max, K-split) ----------------
// grid (32 row-tiles of 128, 8 heads, SPLITS). Wave owns 32 rows (2 frags).
// Q frags pre-scaled by log2(e)/8 so inner loop is exp2(s) directly.
template<int SPLITS>
__global__ __launch_bounds__(256) void attn_kernel(
    const u16* __restrict__ qkv, const u16* __restrict__ vt,
    float* __restrict__ opart, float* __restrict__ lpart)
{
  const int tid = threadIdx.x, wave = tid >> 6, lane = tid & 63;
  const int quad = lane >> 4, l16 = lane & 15;
  const int h = blockIdx.y, tile = blockIdx.x, split = blockIdx.z;

  __shared__ __align__(16) u16 Ks[64][72];    // K tile [m'][d]
  __shared__ __align__(16) u16 Vts[64][72];   // V^T tile [d][m']
  __shared__ __align__(16) u16 Ps[128][72];   // P [row][m']

  const float QSCALE = 0.18033688011112042f;  // log2(e)/8
  bf16x8 aq[2][2];
#pragma unroll
  for (int mb = 0; mb < 2; ++mb) {
    const int qrow = tile * 128 + wave * 32 + mb * 16 + l16;
    const u16* qp = qkv + (size_t)qrow * 1536 + h * 64 + quad * 8;
    u16x8 q0 = *(const u16x8*)qp;
    u16x8 q1 = *(const u16x8*)(qp + 32);
    u16x8 s0, s1;
#pragma unroll
    for (int i = 0; i < 8; ++i) {
      s0[i] = f2b(b2f(q0[i]) * QSCALE);
      s1[i] = f2b(b2f(q1[i]) * QSCALE);
    }
    aq[mb][0] = __builtin_bit_cast(bf16x8, s0);
    aq[mb][1] = __builtin_bit_cast(bf16x8, s1);
  }

  f32x4 O[2][4] = {};
  float lsum[2][4] = {};   // per-lane partial row sums

  const int srow = tid >> 2;          // staging row 0..63
  const int scol = (tid & 3) << 4;    // staging col offset

  const int mt1 = (split + 1) * (64 / SPLITS);
  for (int mt = split * (64 / SPLITS); mt < mt1; ++mt) {
    const u16* kp = qkv + (size_t)(mt * 64 + srow) * 1536 + 512 + h * 64 + scol;
    const u16* vp = vt + (size_t)(h * 64 + srow) * N_NODES + mt * 64 + scol;
    u16x8 k0 = *(const u16x8*)kp;
    u16x8 k1 = *(const u16x8*)(kp + 8);
    u16x8 v0 = *(const u16x8*)vp;
    u16x8 v1 = *(const u16x8*)(vp + 8);
    __syncthreads();                  // prior iter's Ks/Vts reads complete
    *(u16x8*)&Ks[srow][scol]      = k0;
    *(u16x8*)&Ks[srow][scol + 8]  = k1;
    *(u16x8*)&Vts[srow][scol]     = v0;
    *(u16x8*)&Vts[srow][scol + 8] = v1;
    __syncthreads();

    // S = (cQ) K^T
    f32x4 s[2][4] = {};
#pragma unroll
    for (int ks = 0; ks < 2; ++ks) {
      bf16x8 bk[4];
#pragma unroll
      for (int jn = 0; jn < 4; ++jn)
        bk[jn] = *(const bf16x8*)&Ks[jn * 16 + l16][ks * 32 + quad * 8];
#pragma unroll
      for (int mb = 0; mb < 2; ++mb)
#pragma unroll
        for (int jn = 0; jn < 4; ++jn)
          s[mb][jn] = __builtin_amdgcn_mfma_f32_16x16x32_bf16(aq[mb][ks], bk[jn], s[mb][jn], 0, 0, 0);
    }

    // p = exp2(s); accumulate per-lane partial sums; half-up bf16 store
#pragma unroll
    for (int mb = 0; mb < 2; ++mb)
#pragma unroll
      for (int jn = 0; jn < 4; ++jn)
#pragma unroll
        for (int r = 0; r < 4; ++r) {
          float p = __builtin_amdgcn_exp2f(s[mb][jn][r]);
          lsum[mb][r] += p;
          Ps[wave * 32 + mb * 16 + quad * 4 + r][jn * 16 + l16] = f2b_up(p);
        }
    // no barrier: Ps rows are wave-private; lgkmcnt ordering handles RAW

    // O += P V
#pragma unroll
    for (int ks = 0; ks < 2; ++ks) {
      bf16x8 bv[4];
#pragma unroll
      for (int jd = 0; jd < 4; ++jd)
        bv[jd] = *(const bf16x8*)&Vts[jd * 16 + l16][ks * 32 + quad * 8];
#pragma unroll
      for (int mb = 0; mb < 2; ++mb) {
        bf16x8 ap = *(const bf16x8*)&Ps[wave * 32 + mb * 16 + l16][ks * 32 + quad * 8];
#pragma unroll
        for (int jd = 0; jd < 4; ++jd)
          O[mb][jd] = __builtin_amdgcn_mfma_f32_16x16x32_bf16(ap, bv[jd], O[mb][jd], 0, 0, 0);
      }
    }
  }

  // one-time 16-lane reduce of row-sum partials
#pragma unroll
  for (int mb = 0; mb < 2; ++mb)
#pragma unroll
    for (int r = 0; r < 4; ++r)
#pragma unroll
      for (int off = 1; off < 16; off <<= 1)
        lsum[mb][r] += __shfl_xor(lsum[mb][r], off);

  // write unnormalized partials
#pragma unroll
  for (int mb = 0; mb < 2; ++mb)
#pragma unroll
    for (int r = 0; r < 4; ++r) {
      const int row = tile * 128 + wave * 32 + mb * 16 + quad * 4 + r;
      float* orow = opart + ((size_t)split * N_NODES + row) * C_DIM + h * 64;
#pragma unroll
      for (int jd = 0; jd < 4; ++jd)
        orow[jd * 16 + l16] = O[mb][jd][r];
      if (l16 == 0)
        lpart[((size_t)split * N_NODES + row) * H_HEADS + h] = lsum[mb][r];
    }
}

template<int SPLITS>
__global__ __launch_bounds__(256) void attn_combine(
    const float* __restrict__ opart, const float* __restrict__ lpart,
    u16* __restrict__ ctx)
{
  const size_t base = (size_t)(blockIdx.x * 256 + threadIdx.x) * 8;
  const int row = (int)(base >> 9);
  const int h = (int)((base & 511) >> 6);
  float l = 0.0f;
#pragma unroll
  for (int s = 0; s < SPLITS; ++s)
    l += lpart[(size_t)s * N_NODES * H_HEADS + (size_t)row * H_HEADS + h];
  const float inv = 1.0f / l;
  float o[8] = {};
#pragma unroll
  for (int s = 0; s < SPLITS; ++s) {
    const float* op = opart + (size_t)s * N_NODES * C_DIM + base;
    f32x4 p0 = *(const f32x4*)op;
    f32x4 p1 = *(const f32x4*)(op + 4);
#pragma unroll
    for (int i = 0; i < 4; ++i) { o[i] += p0[i]; o[4 + i] += p1[i]; }
  }
  u16x8 ob;
#pragma unroll
  for (int i = 0; i < 8; ++i) ob[i] = f2b(o[i] * inv);
  *(u16x8*)(ctx + base) = ob;
}

// ---------------- LayerNorms (one wave per row) ----------------
__global__ __launch_bounds__(256) void ln1_kernel(
    const float* __restrict__ x, const float* __restrict__ pr,
    const float* __restrict__ g, const float* __restrict__ b,
    u16* __restrict__ hb, float* __restrict__ hf)
{
  const int wave = threadIdx.x >> 6, lane = threadIdx.x & 63;
  const int row = blockIdx.x * 4 + wave;
  const int c0 = lane * 8;
  const size_t base = (size_t)row * C_DIM + c0;
  f32x4 x0 = *(const f32x4*)(x + base);
  f32x4 x1 = *(const f32x4*)(x + base + 4);
  f32x4 p0 = *(const f32x4*)(pr + base);
  f32x4 p1 = *(const f32x4*)(pr + base + 4);
  float v[8];
#pragma unroll
  for (int i = 0; i < 4; ++i) { v[i] = x0[i] + p0[i]; v[4 + i] = x1[i] + p1[i]; }
  float sum = 0, sq = 0;
#pragma unroll
  for (int i = 0; i < 8; ++i) { sum += v[i]; sq += v[i] * v[i]; }
  for (int off = 1; off < 64; off <<= 1) { sum += __shfl_xor(sum, off); sq += __shfl_xor(sq, off); }
  const float mean = sum * (1.0f / C_DIM);
  const float var  = sq * (1.0f / C_DIM) - mean * mean;
  const float rstd = rsqrtf(var + 1e-5f);
  f32x4 g0 = *(const f32x4*)(g + c0), g1 = *(const f32x4*)(g + c0 + 4);
  f32x4 b0 = *(const f32x4*)(b + c0), b1 = *(const f32x4*)(b + c0 + 4);
  u16x8 ob; f32x4 h0, h1;
#pragma unroll
  for (int i = 0; i < 4; ++i) {
    float hv0 = (v[i]     - mean) * rstd * g0[i] + b0[i];
    float hv1 = (v[4 + i] - mean) * rstd * g1[i] + b1[i];
    h0[i] = hv0; h1[i] = hv1;
    ob[i] = f2b(hv0); ob[4 + i] = f2b(hv1);
  }
  *(u16x8*)(hb + base) = ob;
  *(f32x4*)(hf + base) = h0;
  *(f32x4*)(hf + base + 4) = h1;
}

__global__ __launch_bounds__(256) void ln2_kernel(
    const float* __restrict__ a, const float* __restrict__ c,
    const float* __restrict__ g, const float* __restrict__ b,
    float* __restrict__ out)
{
  const int wave = threadIdx.x >> 6, lane = threadIdx.x & 63;
  const int row = blockIdx.x * 4 + wave;
  const int c0 = lane * 8;
  const size_t base = (size_t)row * C_DIM + c0;
  f32x4 a0 = *(const f32x4*)(a + base), a1 = *(const f32x4*)(a + base + 4);
  f32x4 c0v = *(const f32x4*)(c + base), c1v = *(const f32x4*)(c + base + 4);
  float v[8];
#pragma unroll
  for (int i = 0; i < 4; ++i) { v[i] = a0[i] + c0v[i]; v[4 + i] = a1[i] + c1v[i]; }
  float sum = 0, sq = 0;
#pragma unroll
  for (int i = 0; i < 8; ++i) { sum += v[i]; sq += v[i] * v[i]; }
  for (int off = 1; off < 64; off <<= 1) { sum += __shfl_xor(sum, off); sq += __shfl_xor(sq, off); }
  const float mean = sum * (1.0f / C_DIM);
  const float var  = sq * (1.0f / C_DIM) - mean * mean;
  const float rstd = rsqrtf(var + 1e-5f);
  f32x4 g0 = *(const f32x4*)(g + c0), g1 = *(const f32x4*)(g + c0 + 4);
  f32x4 b0 = *(const f32x4*)(b + c0), b1 = *(const f32x4*)(b + c0 + 4);
  f32x4 h0, h1;
#pragma unroll
  for (int i = 0; i < 4; ++i) {
    h0[i] = (v[i]     - mean) * rstd * g0[i] + b0[i];
    h1[i] = (v[4 + i] - mean) * rstd * g1[i] + b1[i];
  }
  *(f32x4*)(out + base) = h0;
  *(f32x4*)(out + base + 4) = h1;
}

// ---------------- launch ----------------
extern "C" void kernel_launch(void* const* d_in, const int* in_sizes, int n_in,
                              void* d_out, int out_size, void* d_ws, size_t ws_size,
                              hipStream_t stream) {
  const float* x          = (const float*)d_in[0];
  const int*   ei         = (const int*)d_in[1];
  const float* local_w    = (const float*)d_in[2];
  const float* local_b    = (const float*)d_in[3];
  const float* in_proj_w  = (const float*)d_in[4];
  const float* in_proj_b  = (const float*)d_in[5];
  const float* attn_out_w = (const float*)d_in[6];
  const float* attn_out_b = (const float*)d_in[7];
  const float* output_w   = (const float*)d_in[8];
  const float* output_b   = (const float*)d_in[9];
  const float* n1g = (const float*)d_in[10];
  const float* n1b = (const float*)d_in[11];
  const float* n2g = (const float*)d_in[12];
  const float* n2b = (const float*)d_in[13];
  const float* ffn_w1 = (const float*)d_in[14];
  const float* ffn_b1 = (const float*)d_in[15];
  const float* ffn_w2 = (const float*)d_in[16];
  const float* ffn_b2 = (const float*)d_in[17];
  float* out = (float*)d_out;

  char* ws = (char*)d_ws;
  size_t o = 0;
  float* local_out = (float*)(ws + o); o += (size_t)N_NODES * C_DIM * 4;  // 8 MB
  int* deg    = (int*)(ws + o); o += (N_NODES) * 4;
  int* off    = (int*)(ws + o); o += (N_NODES + 16) * 4;
  int* cursor = (int*)(ws + o); o += (N_NODES) * 4;
  int* csr    = (int*)(ws + o); o += (size_t)E_EDGES * 4;
  u16* xb   = (u16*)(ws + o); o += (size_t)N_NODES * C_DIM * 2;           // 4 MB
  u16* wbLQ = (u16*)(ws + o); o += (size_t)4 * C_DIM * C_DIM * 2;         // 2 MB
  u16* wbA  = (u16*)(ws + o); o += (size_t)C_DIM * C_DIM * 2;
  u16* wbO  = (u16*)(ws + o); o += (size_t)C_DIM * C_DIM * 2;
  u16* wbF1 = (u16*)(ws + o); o += (size_t)2 * C_DIM * C_DIM * 2;
  u16* wbF2 = (u16*)(ws + o); o += (size_t)2 * C_DIM * C_DIM * 2;
  u16* local_h   = (u16*)(ws + o); o += (size_t)N_NODES * C_DIM * 2;
  u16* qkvb      = (u16*)(ws + o); o += (size_t)N_NODES * 3 * C_DIM * 2;  // 12 MB
  u16* ctxb      = (u16*)(ws + o); o += (size_t)N_NODES * C_DIM * 2;
  u16* mixed     = (u16*)(ws + o); o += (size_t)N_NODES * C_DIM * 2;
  u16* hidden_bf = (u16*)(ws + o); o += (size_t)N_NODES * C_DIM * 2;      // 4 MB
  float* hidden_f = (float*)(ws + o); o += (size_t)N_NODES * C_DIM * 4;   // 8 MB
  u16* ff1       = (u16*)(ws + o); o += (size_t)N_NODES * 2 * C_DIM * 2;  // 8 MB
  // aliases (dead ranges reused):
  float* proj  = (float*)qkvb;       // qkv dead after attn; proj 8 MB <= 12 MB
  float* ff2   = (float*)local_out;  // local_out dead after mix-epilogue gemm
  u16*   vt    = xb;                 // xb dead after LQKV gemm; 4 MB
  // SPLITS=4 scratch (32.5 MB) goes past ff1 if workspace allows
  float* opart4 = (float*)(ws + o);
  float* lpart4 = (float*)(ws + o + (size_t)4 * N_NODES * C_DIM * 4);
  const size_t need4 = o + (size_t)4 * N_NODES * C_DIM * 4 + (size_t)4 * N_NODES * H_HEADS * 4;
  const bool use4 = (ws_size >= need4);
  // SPLITS=2 fallback: inside hidden_bf..ff1 region (16.25 MB <= 20 MB)
  float* opart2 = (float*)hidden_bf;
  float* lpart2 = opart2 + (size_t)2 * N_NODES * C_DIM;

  (void)hipMemsetAsync(deg, 0, N_NODES * 4, stream);

  // fp32 -> bf16 conversions (x + weights) + fused degree histogram
  CvtArgs ca;
  ca.src[0] = x;          ca.dst[0] = xb;   ca.n[0] = N_NODES * C_DIM;
  ca.src[1] = local_w;    ca.dst[1] = wbLQ;                  ca.n[1] = C_DIM * C_DIM;
  ca.src[2] = in_proj_w;  ca.dst[2] = wbLQ + C_DIM * C_DIM;  ca.n[2] = 3 * C_DIM * C_DIM;
  ca.src[3] = attn_out_w; ca.dst[3] = wbA;  ca.n[3] = C_DIM * C_DIM;
  ca.src[4] = output_w;   ca.dst[4] = wbO;  ca.n[4] = C_DIM * C_DIM;
  ca.src[5] = ffn_w1;     ca.dst[5] = wbF1; ca.n[5] = 2 * C_DIM * C_DIM;
  ca.src[6] = ffn_w2;     ca.dst[6] = wbF2; ca.n[6] = 2 * C_DIM * C_DIM;
  ca.ei = ei; ca.deg = deg;
  cvt_multi<<<dim3(N_NODES * C_DIM / 2048, 8), 256, 0, stream>>>(ca);

  // CSR build
  scan_kernel<<<1, 256, 0, stream>>>(deg, off, cursor);
  fill_kernel<<<E_EDGES / 256, 256, 0, stream>>>(ei, cursor, csr);

  // merged local+qkv GEMM: [local_h | qkvb] = xb @ [local_w; in_proj_w]^T
  gemm128<0><<<dim3(32, 16), 256, 0, stream>>>(xb, wbLQ, local_b, in_proj_b,
      local_h, qkvb, N_NODES, 4 * C_DIM, C_DIM);
  gather_kernel<<<N_NODES / 4, 256, 0, stream>>>(off, csr, local_h, local_out);

  // global branch
  vtrans_kernel<<<dim3(64, 8), 256, 0, stream>>>(qkvb, vt);   // xb dead now
  if (use4) {
    attn_kernel<4><<<dim3(32, 8, 4), 256, 0, stream>>>(qkvb, vt, opart4, lpart4);
    attn_combine<4><<<N_NODES * C_DIM / 2048, 256, 0, stream>>>(opart4, lpart4, ctxb);
  } else {
    attn_kernel<2><<<dim3(32, 8, 2), 256, 0, stream>>>(qkvb, vt, opart2, lpart2);
    attn_combine<2><<<N_NODES * C_DIM / 2048, 256, 0, stream>>>(opart2, lpart2, ctxb);
  }

  // mixed = 0.5*local_out + 0.5*(ctx @ attn_out_w^T + b)
  gemm_bt<3><<<dim3(64, 8), 256, 0, stream>>>(ctxb, wbA, attn_out_b, mixed,
      N_NODES, C_DIM, C_DIM, local_out);

  // proj = mixed @ output_w^T + b ; hidden = LN(x + proj)
  gemm_bt<1><<<dim3(64, 8), 256, 0, stream>>>(mixed, wbO, output_b, proj,
      N_NODES, C_DIM, C_DIM, nullptr);
  ln1_kernel<<<N_NODES / 4, 256, 0, stream>>>(x, proj, n1g, n1b, hidden_bf, hidden_f);

  // FFN
  gemm128<2><<<dim3(32, 8), 256, 0, stream>>>(hidden_bf, wbF1, ffn_b1, nullptr,
      ff1, nullptr, N_NODES, 2 * C_DIM, C_DIM);
  gemm_bt<1><<<dim3(64, 8), 256, 0, stream>>>(ff1, wbF2, ffn_b2, ff2,
      N_NODES, C_DIM, 2 * C_DIM, nullptr);
  ln2_kernel<<<N_NODES / 4, 256, 0, stream>>>(hidden_f, ff2, n2g, n2b, out);
}

// Round 8
// 290.348 us; speedup vs baseline: 1.0432x; 1.0189x over previous
//
#include <hip/hip_runtime.h>

// SGFormer encoder layer, MI355X gfx950.
// fp32 I/O per reference dtypes; bf16 MFMA internally (error ~0.03 << 0.1 thr).
// R2: scatter-mean via CSR build + gather (was 1800us of fp32 atomics = 85%).
// R3/R4: static-max softmax flash attn, pre-transposed V, K-split partials.
// R5: SPLITS=4, Q-frag prescale, merged LQKV gemm (128-tile), fused hist.
// R6 REGRESSED (parity P staging); R7 reverted + f2b_up P writes.
// R8: global_load_lds width=16 staging for all GEMMs + attn K/V tiles, with
//     XOR granule swizzle (slot = g ^ (row&7)) replacing the +8 pad: frag
//     b128 reads land 2 lanes/bank (free); staging is 1 instr per 1KB/wave.

#define N_NODES 4096
#define C_DIM   512
#define H_HEADS 8
#define D_HEAD  64
#define E_EDGES 131072

typedef unsigned short u16;
typedef unsigned int   u32;
typedef u16   u16x8  __attribute__((ext_vector_type(8)));
typedef __bf16 bf16x8 __attribute__((ext_vector_type(8)));
typedef float  f32x4  __attribute__((ext_vector_type(4)));

__device__ __forceinline__ float b2f(u16 u) {
  unsigned int i = ((unsigned int)u) << 16;
  return __builtin_bit_cast(float, i);
}
__device__ __forceinline__ u16 f2b(float f) {
  unsigned int i = __builtin_bit_cast(unsigned int, f);
  i += 0x7fffu + ((i >> 16) & 1u);   // RNE
  return (u16)(i >> 16);
}
__device__ __forceinline__ u16 f2b_up(float f) {   // round-half-up (cheaper)
  unsigned int i = __builtin_bit_cast(unsigned int, f);
  return (u16)((i + 0x8000u) >> 16);
}
// async global->LDS, 16B per lane; LDS dest = wave-uniform base + lane*16
__device__ __forceinline__ void glds16(const u16* g, u16* l) {
  __builtin_amdgcn_global_load_lds(
      (const __attribute__((address_space(1))) void*)g,
      (__attribute__((address_space(3))) void*)l, 16, 0, 0);
}

// ---------------- fp32 -> bf16 batched convert (+ fused hist) ----------------
struct CvtArgs {
  const float* src[7];
  u16* dst[7];
  int n[7];
  const int* ei;
  int* deg;
};

__global__ __launch_bounds__(256) void cvt_multi(CvtArgs a) {
  const int t = blockIdx.y;
  if (t == 7) {                       // fused degree histogram
    if (blockIdx.x >= E_EDGES / 256) return;
    const int e = blockIdx.x * 256 + threadIdx.x;
    atomicAdd(&a.deg[a.ei[E_EDGES + e]], 1);
    return;
  }
  const int i = (blockIdx.x * 256 + threadIdx.x) * 8;
  if (i >= a.n[t]) return;
  const float* s = a.src[t] + i;
  f32x4 v0 = *(const f32x4*)s;
  f32x4 v1 = *(const f32x4*)(s + 4);
  u16x8 o;
  o[0]=f2b(v0[0]); o[1]=f2b(v0[1]); o[2]=f2b(v0[2]); o[3]=f2b(v0[3]);
  o[4]=f2b(v1[0]); o[5]=f2b(v1[1]); o[6]=f2b(v1[2]); o[7]=f2b(v1[3]);
  *(u16x8*)(a.dst[t] + i) = o;
}

// ---------------- 64x64 tile GEMM: out = A[M,K] * W[Nout,K]^T + bias --------
// EPI: 1 = f32 out, 3 = 0.5*local+0.5*v -> bf16
// glls staging, XOR-swizzled LDS (slot = granule ^ (row&7)).
template<int EPI>
__global__ __launch_bounds__(256) void gemm_bt(
    const u16* __restrict__ A, const u16* __restrict__ W,
    const float* __restrict__ bias, void* __restrict__ outp,
    int M, int Nout, int K,
    const float* __restrict__ mloc)
{
  const int tid  = threadIdx.x;
  const int lane = tid & 63, wave = tid >> 6;
  const int quad = lane >> 4, l16 = lane & 15;
  const int wm = wave >> 1, wn = wave & 1;   // 2x2 wave grid, 32x32 per wave
  const int bm = blockIdx.x, bnb = blockIdx.y;

  __shared__ __align__(16) u16 As[64][64];
  __shared__ __align__(16) u16 Ws[64][64];

  f32x4 acc[2][2] = {};

  // staging: lane covers (row = base + lane/8, granule gs = lane&7);
  // src granule = gs ^ lr so that LDS slot gs holds global granule gs^(row&7)
  const int lr = lane >> 3, gs = lane & 7;
  const int g8 = (gs ^ lr) * 8;                  // u16 offset within row
  const u16* a0 = A + (size_t)(bm  * 64 + wave * 16 +     lr) * K + g8;
  const u16* a1 = A + (size_t)(bm  * 64 + wave * 16 + 8 + lr) * K + g8;
  const u16* w0 = W + (size_t)(bnb * 64 + wave * 16 +     lr) * K + g8;
  const u16* w1 = W + (size_t)(bnb * 64 + wave * 16 + 8 + lr) * K + g8;

  for (int k0 = 0; k0 < K; k0 += 64) {
    __syncthreads();                  // prior iter's LDS reads complete
    glds16(a0 + k0, &As[wave * 16][0]);
    glds16(a1 + k0, &As[wave * 16 + 8][0]);
    glds16(w0 + k0, &Ws[wave * 16][0]);
    glds16(w1 + k0, &Ws[wave * 16 + 8][0]);
    __syncthreads();                  // drains vmcnt (glls) before reads
#pragma unroll
    for (int ks = 0; ks < 2; ++ks) {
      const int slot = ((ks * 4 + quad) ^ (l16 & 7)) * 8;
      bf16x8 af[2], bf[2];
      af[0] = *(const bf16x8*)&As[wm * 32 +      l16][slot];
      af[1] = *(const bf16x8*)&As[wm * 32 + 16 + l16][slot];
      bf[0] = *(const bf16x8*)&Ws[wn * 32 +      l16][slot];
      bf[1] = *(const bf16x8*)&Ws[wn * 32 + 16 + l16][slot];
#pragma unroll
      for (int i = 0; i < 2; ++i)
#pragma unroll
        for (int j = 0; j < 2; ++j)
          acc[i][j] = __builtin_amdgcn_mfma_f32_16x16x32_bf16(af[i], bf[j], acc[i][j], 0, 0, 0);
    }
  }

#pragma unroll
  for (int i = 0; i < 2; ++i)
#pragma unroll
    for (int j = 0; j < 2; ++j) {
      const int col = bnb * 64 + wn * 32 + j * 16 + l16;
      const float bias_v = bias[col];
#pragma unroll
      for (int r = 0; r < 4; ++r) {
        const int row = bm * 64 + wm * 32 + i * 16 + quad * 4 + r;
        float v = acc[i][j][r] + bias_v;
        const size_t o = (size_t)row * Nout + col;
        if constexpr (EPI == 1) {
          ((float*)outp)[o] = v;
        } else {
          ((u16*)outp)[o] = f2b(0.5f * mloc[o] + 0.5f * v);
        }
      }
    }
}

// ---------------- 128x128 tile GEMM (m97-class: glls staging) ----------------
// MODE 0: split LQKV epilogue (col<512 -> out0=local_h[.,512],
//         else out1=qkvb[.,1536] with bias1), bf16 out
// MODE 2: gelu -> bf16 out0 (stride Nout)
template<int MODE>
__global__ __launch_bounds__(256) void gemm128(
    const u16* __restrict__ A, const u16* __restrict__ W,
    const float* __restrict__ bias0, const float* __restrict__ bias1,
    u16* __restrict__ out0, u16* __restrict__ out1,
    int M, int Nout, int K)
{
  const int tid  = threadIdx.x;
  const int lane = tid & 63, wave = tid >> 6;
  const int quad = lane >> 4, l16 = lane & 15;
  const int wm = wave >> 1, wn = wave & 1;   // 2x2 wave grid, 64x64 per wave
  const int bm = blockIdx.x, bnb = blockIdx.y;

  __shared__ __align__(16) u16 As[128][64];
  __shared__ __align__(16) u16 Ws[128][64];

  f32x4 acc[4][4] = {};

  const int lr = lane >> 3, gs = lane & 7;
  const int g8 = (gs ^ lr) * 8;
  const u16* ab = A + (size_t)(bm  * 128 + wave * 32 + lr) * K + g8;
  const u16* wb = W + (size_t)(bnb * 128 + wave * 32 + lr) * K + g8;

  for (int k0 = 0; k0 < K; k0 += 64) {
    __syncthreads();
#pragma unroll
    for (int c = 0; c < 4; ++c) {
      glds16(ab + (size_t)(c * 8) * K + k0, &As[wave * 32 + c * 8][0]);
      glds16(wb + (size_t)(c * 8) * K + k0, &Ws[wave * 32 + c * 8][0]);
    }
    __syncthreads();
#pragma unroll
    for (int ks = 0; ks < 2; ++ks) {
      const int slot = ((ks * 4 + quad) ^ (l16 & 7)) * 8;
      bf16x8 af[4], bf[4];
#pragma unroll
      for (int am = 0; am < 4; ++am)
        af[am] = *(const bf16x8*)&As[wm * 64 + am * 16 + l16][slot];
#pragma unroll
      for (int bn = 0; bn < 4; ++bn)
        bf[bn] = *(const bf16x8*)&Ws[wn * 64 + bn * 16 + l16][slot];
#pragma unroll
      for (int am = 0; am < 4; ++am)
#pragma unroll
        for (int bn = 0; bn < 4; ++bn)
          acc[am][bn] = __builtin_amdgcn_mfma_f32_16x16x32_bf16(af[am], bf[bn], acc[am][bn], 0, 0, 0);
    }
  }

#pragma unroll
  for (int am = 0; am < 4; ++am)
#pragma unroll
    for (int bn = 0; bn < 4; ++bn) {
      const int col = bnb * 128 + wn * 64 + bn * 16 + l16;
      float bias_v;
      if constexpr (MODE == 0) bias_v = (col < 512) ? bias0[col] : bias1[col - 512];
      else                     bias_v = bias0[col];
#pragma unroll
      for (int r = 0; r < 4; ++r) {
        const int row = bm * 128 + wm * 64 + am * 16 + quad * 4 + r;
        float v = acc[am][bn][r] + bias_v;
        if constexpr (MODE == 0) {
          if (col < 512) out0[(size_t)row * 512 + col] = f2b(v);
          else           out1[(size_t)row * 1536 + (col - 512)] = f2b(v);
        } else {
          float gl = 0.5f * v * (1.0f + erff(v * 0.70710678118654752f));
          out0[(size_t)row * Nout + col] = f2b(gl);
        }
      }
    }
}

// ---------------- CSR build (by destination) ----------------
__global__ __launch_bounds__(256) void scan_kernel(
    const int* __restrict__ deg, int* __restrict__ off, int* __restrict__ cursor)
{
  __shared__ int part[256];
  const int t = threadIdx.x;
  int v[16];
  int s = 0;
#pragma unroll
  for (int i = 0; i < 16; ++i) { v[i] = deg[t * 16 + i]; s += v[i]; }
  part[t] = s;
  __syncthreads();
  for (int d = 1; d < 256; d <<= 1) {
    int val = (t >= d) ? part[t - d] : 0;
    __syncthreads();
    if (t >= d) part[t] += val;
    __syncthreads();
  }
  int prefix = (t == 0) ? 0 : part[t - 1];
#pragma unroll
  for (int i = 0; i < 16; ++i) {
    off[t * 16 + i] = prefix;
    cursor[t * 16 + i] = prefix;
    prefix += v[i];
  }
  if (t == 255) off[4096] = prefix;
}

__global__ __launch_bounds__(256) void fill_kernel(
    const int* __restrict__ ei, int* __restrict__ cursor, int* __restrict__ csr)
{
  const int e = blockIdx.x * 256 + threadIdx.x;
  const int s = ei[e];
  const int d = ei[E_EDGES + e];
  const int p = atomicAdd(&cursor[d], 1);
  csr[p] = s;
}

// gather-mean: one wave per dst node; coalesced 1KB row reads (L2-resident)
__global__ __launch_bounds__(256) void gather_kernel(
    const int* __restrict__ off, const int* __restrict__ csr,
    const u16* __restrict__ lh, float* __restrict__ lo)
{
  const int wave = threadIdx.x >> 6, lane = threadIdx.x & 63;
  const int n = blockIdx.x * 4 + wave;
  const int j0 = off[n], j1 = off[n + 1];
  float acc[8] = {};
  for (int j = j0; j < j1; ++j) {
    const int s = csr[j];
    const u16x8 v = *(const u16x8*)(lh + (size_t)s * C_DIM + lane * 8);
#pragma unroll
    for (int i = 0; i < 8; ++i) acc[i] += b2f(v[i]);
  }
  const float inv = 1.0f / fmaxf((float)(j1 - j0), 1.0f);
  f32x4 o0, o1;
#pragma unroll
  for (int i = 0; i < 4; ++i) { o0[i] = acc[i] * inv; o1[i] = acc[4 + i] * inv; }
  float* op = lo + (size_t)n * C_DIM + lane * 8;
  *(f32x4*)op = o0;
  *(f32x4*)(op + 4) = o1;
}

// ---------------- V transpose pack: vt[h][d][m] = V[m][h][d] ----------------
__global__ __launch_bounds__(256) void vtrans_kernel(
    const u16* __restrict__ qkv, u16* __restrict__ vt)
{
  const int tid = threadIdx.x;
  const int d = tid & 63, mg = tid >> 6;   // mg 0..3
  const int h = blockIdx.y, mt = blockIdx.x;
  const int m0 = mt * 64 + mg * 16;
  u16 buf[16];
#pragma unroll
  for (int i = 0; i < 16; ++i)
    buf[i] = qkv[(size_t)(m0 + i) * 1536 + 1024 + h * 64 + d];
  u16x8 w0, w1;
#pragma unroll
  for (int i = 0; i < 8; ++i) { w0[i] = buf[i]; w1[i] = buf[8 + i]; }
  u16* op = vt + (size_t)(h * 64 + d) * N_NODES + m0;
  *(u16x8*)op = w0;
  *(u16x8*)(op + 8) = w1;
}

// ---------------- flash attention (static max, K-split, glls staging) -------
// grid (32 row-tiles of 128, 8 heads, SPLITS). Wave owns 32 rows (2 frags).
// Q frags pre-scaled by log2(e)/8 so inner loop is exp2(s) directly.
template<int SPLITS>
__global__ __launch_bounds__(256) void attn_kernel(
    const u16* __restrict__ qkv, const u16* __restrict__ vt,
    float* __restrict__ opart, float* __restrict__ lpart)
{
  const int tid = threadIdx.x, wave = tid >> 6, lane = tid & 63;
  const int quad = lane >> 4, l16 = lane & 15;
  const int h = blockIdx.y, tile = blockIdx.x, split = blockIdx.z;

  __shared__ __align__(16) u16 Ks[64][64];    // K tile, XOR-swizzled
  __shared__ __align__(16) u16 Vts[64][64];   // V^T tile, XOR-swizzled
  __shared__ __align__(16) u16 Ps[128][72];   // P [row][m'] (padded, VALU-written)

  const float QSCALE = 0.18033688011112042f;  // log2(e)/8
  bf16x8 aq[2][2];
#pragma unroll
  for (int mb = 0; mb < 2; ++mb) {
    const int qrow = tile * 128 + wave * 32 + mb * 16 + l16;
    const u16* qp = qkv + (size_t)qrow * 1536 + h * 64 + quad * 8;
    u16x8 q0 = *(const u16x8*)qp;
    u16x8 q1 = *(const u16x8*)(qp + 32);
    u16x8 s0, s1;
#pragma unroll
    for (int i = 0; i < 8; ++i) {
      s0[i] = f2b(b2f(q0[i]) * QSCALE);
      s1[i] = f2b(b2f(q1[i]) * QSCALE);
    }
    aq[mb][0] = __builtin_bit_cast(bf16x8, s0);
    aq[mb][1] = __builtin_bit_cast(bf16x8, s1);
  }

  f32x4 O[2][4] = {};
  float lsum[2][4] = {};   // per-lane partial row sums

  const int lr = lane >> 3, gs = lane & 7;
  const int g8 = (gs ^ lr) * 8;
  const int R0 = wave * 16 + lr;      // staging rows R0, R0+8

  const int mt1 = (split + 1) * (64 / SPLITS);
  for (int mt = split * (64 / SPLITS); mt < mt1; ++mt) {
    __syncthreads();                  // prior iter's Ks/Vts reads complete
    glds16(qkv + (size_t)(mt * 64 + R0)     * 1536 + 512 + h * 64 + g8, &Ks[wave * 16][0]);
    glds16(qkv + (size_t)(mt * 64 + R0 + 8) * 1536 + 512 + h * 64 + g8, &Ks[wave * 16 + 8][0]);
    glds16(vt + (size_t)(h * 64 + R0)     * N_NODES + mt * 64 + g8, &Vts[wave * 16][0]);
    glds16(vt + (size_t)(h * 64 + R0 + 8) * N_NODES + mt * 64 + g8, &Vts[wave * 16 + 8][0]);
    __syncthreads();                  // drains vmcnt before LDS reads

    // S = (cQ) K^T
    f32x4 s[2][4] = {};
#pragma unroll
    for (int ks = 0; ks < 2; ++ks) {
      const int slot = ((ks * 4 + quad) ^ (l16 & 7)) * 8;
      bf16x8 bk[4];
#pragma unroll
      for (int jn = 0; jn < 4; ++jn)
        bk[jn] = *(const bf16x8*)&Ks[jn * 16 + l16][slot];
#pragma unroll
      for (int mb = 0; mb < 2; ++mb)
#pragma unroll
        for (int jn = 0; jn < 4; ++jn)
          s[mb][jn] = __builtin_amdgcn_mfma_f32_16x16x32_bf16(aq[mb][ks], bk[jn], s[mb][jn], 0, 0, 0);
    }

    // p = exp2(s); accumulate per-lane partial sums; half-up bf16 store
#pragma unroll
    for (int mb = 0; mb < 2; ++mb)
#pragma unroll
      for (int jn = 0; jn < 4; ++jn)
#pragma unroll
        for (int r = 0; r < 4; ++r) {
          float p = __builtin_amdgcn_exp2f(s[mb][jn][r]);
          lsum[mb][r] += p;
          Ps[wave * 32 + mb * 16 + quad * 4 + r][jn * 16 + l16] = f2b_up(p);
        }
    // no barrier: Ps rows are wave-private; lgkmcnt ordering handles RAW

    // O += P V
#pragma unroll
    for (int ks = 0; ks < 2; ++ks) {
      const int slot = ((ks * 4 + quad) ^ (l16 & 7)) * 8;
      bf16x8 bv[4];
#pragma unroll
      for (int jd = 0; jd < 4; ++jd)
        bv[jd] = *(const bf16x8*)&Vts[jd * 16 + l16][slot];
#pragma unroll
      for (int mb = 0; mb < 2; ++mb) {
        bf16x8 ap = *(const bf16x8*)&Ps[wave * 32 + mb * 16 + l16][ks * 32 + quad * 8];
#pragma unroll
        for (int jd = 0; jd < 4; ++jd)
          O[mb][jd] = __builtin_amdgcn_mfma_f32_16x16x32_bf16(ap, bv[jd], O[mb][jd], 0, 0, 0);
      }
    }
  }

  // one-time 16-lane reduce of row-sum partials
#pragma unroll
  for (int mb = 0; mb < 2; ++mb)
#pragma unroll
    for (int r = 0; r < 4; ++r)
#pragma unroll
      for (int off = 1; off < 16; off <<= 1)
        lsum[mb][r] += __shfl_xor(lsum[mb][r], off);

  // write unnormalized partials
#pragma unroll
  for (int mb = 0; mb < 2; ++mb)
#pragma unroll
    for (int r = 0; r < 4; ++r) {
      const int row = tile * 128 + wave * 32 + mb * 16 + quad * 4 + r;
      float* orow = opart + ((size_t)split * N_NODES + row) * C_DIM + h * 64;
#pragma unroll
      for (int jd = 0; jd < 4; ++jd)
        orow[jd * 16 + l16] = O[mb][jd][r];
      if (l16 == 0)
        lpart[((size_t)split * N_NODES + row) * H_HEADS + h] = lsum[mb][r];
    }
}

template<int SPLITS>
__global__ __launch_bounds__(256) void attn_combine(
    const float* __restrict__ opart, const float* __restrict__ lpart,
    u16* __restrict__ ctx)
{
  const size_t base = (size_t)(blockIdx.x * 256 + threadIdx.x) * 8;
  const int row = (int)(base >> 9);
  const int h = (int)((base & 511) >> 6);
  float l = 0.0f;
#pragma unroll
  for (int s = 0; s < SPLITS; ++s)
    l += lpart[(size_t)s * N_NODES * H_HEADS + (size_t)row * H_HEADS + h];
  const float inv = 1.0f / l;
  float o[8] = {};
#pragma unroll
  for (int s = 0; s < SPLITS; ++s) {
    const float* op = opart + (size_t)s * N_NODES * C_DIM + base;
    f32x4 p0 = *(const f32x4*)op;
    f32x4 p1 = *(const f32x4*)(op + 4);
#pragma unroll
    for (int i = 0; i < 4; ++i) { o[i] += p0[i]; o[4 + i] += p1[i]; }
  }
  u16x8 ob;
#pragma unroll
  for (int i = 0; i < 8; ++i) ob[i] = f2b(o[i] * inv);
  *(u16x8*)(ctx + base) = ob;
}

// ---------------- LayerNorms (one wave per row) ----------------
__global__ __launch_bounds__(256) void ln1_kernel(
    const float* __restrict__ x, const float* __restrict__ pr,
    const float* __restrict__ g, const float* __restrict__ b,
    u16* __restrict__ hb, float* __restrict__ hf)
{
  const int wave = threadIdx.x >> 6, lane = threadIdx.x & 63;
  const int row = blockIdx.x * 4 + wave;
  const int c0 = lane * 8;
  const size_t base = (size_t)row * C_DIM + c0;
  f32x4 x0 = *(const f32x4*)(x + base);
  f32x4 x1 = *(const f32x4*)(x + base + 4);
  f32x4 p0 = *(const f32x4*)(pr + base);
  f32x4 p1 = *(const f32x4*)(pr + base + 4);
  float v[8];
#pragma unroll
  for (int i = 0; i < 4; ++i) { v[i] = x0[i] + p0[i]; v[4 + i] = x1[i] + p1[i]; }
  float sum = 0, sq = 0;
#pragma unroll
  for (int i = 0; i < 8; ++i) { sum += v[i]; sq += v[i] * v[i]; }
  for (int off = 1; off < 64; off <<= 1) { sum += __shfl_xor(sum, off); sq += __shfl_xor(sq, off); }
  const float mean = sum * (1.0f / C_DIM);
  const float var  = sq * (1.0f / C_DIM) - mean * mean;
  const float rstd = rsqrtf(var + 1e-5f);
  f32x4 g0 = *(const f32x4*)(g + c0), g1 = *(const f32x4*)(g + c0 + 4);
  f32x4 b0 = *(const f32x4*)(b + c0), b1 = *(const f32x4*)(b + c0 + 4);
  u16x8 ob; f32x4 h0, h1;
#pragma unroll
  for (int i = 0; i < 4; ++i) {
    float hv0 = (v[i]     - mean) * rstd * g0[i] + b0[i];
    float hv1 = (v[4 + i] - mean) * rstd * g1[i] + b1[i];
    h0[i] = hv0; h1[i] = hv1;
    ob[i] = f2b(hv0); ob[4 + i] = f2b(hv1);
  }
  *(u16x8*)(hb + base) = ob;
  *(f32x4*)(hf + base) = h0;
  *(f32x4*)(hf + base + 4) = h1;
}

__global__ __launch_bounds__(256) void ln2_kernel(
    const float* __restrict__ a, const float* __restrict__ c,
    const float* __restrict__ g, const float* __restrict__ b,
    float* __restrict__ out)
{
  const int wave = threadIdx.x >> 6, lane = threadIdx.x & 63;
  const int row = blockIdx.x * 4 + wave;
  const int c0 = lane * 8;
  const size_t base = (size_t)row * C_DIM + c0;
  f32x4 a0 = *(const f32x4*)(a + base), a1 = *(const f32x4*)(a + base + 4);
  f32x4 c0v = *(const f32x4*)(c + base), c1v = *(const f32x4*)(c + base + 4);
  float v[8];
#pragma unroll
  for (int i = 0; i < 4; ++i) { v[i] = a0[i] + c0v[i]; v[4 + i] = a1[i] + c1v[i]; }
  float sum = 0, sq = 0;
#pragma unroll
  for (int i = 0; i < 8; ++i) { sum += v[i]; sq += v[i] * v[i]; }
  for (int off = 1; off < 64; off <<= 1) { sum += __shfl_xor(sum, off); sq += __shfl_xor(sq, off); }
  const float mean = sum * (1.0f / C_DIM);
  const float var  = sq * (1.0f / C_DIM) - mean * mean;
  const float rstd = rsqrtf(var + 1e-5f);
  f32x4 g0 = *(const f32x4*)(g + c0), g1 = *(const f32x4*)(g + c0 + 4);
  f32x4 b0 = *(const f32x4*)(b + c0), b1 = *(const f32x4*)(b + c0 + 4);
  f32x4 h0, h1;
#pragma unroll
  for (int i = 0; i < 4; ++i) {
    h0[i] = (v[i]     - mean) * rstd * g0[i] + b0[i];
    h1[i] = (v[4 + i] - mean) * rstd * g1[i] + b1[i];
  }
  *(f32x4*)(out + base) = h0;
  *(f32x4*)(out + base + 4) = h1;
}

// ---------------- launch ----------------
extern "C" void kernel_launch(void* const* d_in, const int* in_sizes, int n_in,
                              void* d_out, int out_size, void* d_ws, size_t ws_size,
                              hipStream_t stream) {
  const float* x          = (const float*)d_in[0];
  const int*   ei         = (const int*)d_in[1];
  const float* local_w    = (const float*)d_in[2];
  const float* local_b    = (const float*)d_in[3];
  const float* in_proj_w  = (const float*)d_in[4];
  const float* in_proj_b  = (const float*)d_in[5];
  const float* attn_out_w = (const float*)d_in[6];
  const float* attn_out_b = (const float*)d_in[7];
  const float* output_w   = (const float*)d_in[8];
  const float* output_b   = (const float*)d_in[9];
  const float* n1g = (const float*)d_in[10];
  const float* n1b = (const float*)d_in[11];
  const float* n2g = (const float*)d_in[12];
  const float* n2b = (const float*)d_in[13];
  const float* ffn_w1 = (const float*)d_in[14];
  const float* ffn_b1 = (const float*)d_in[15];
  const float* ffn_w2 = (const float*)d_in[16];
  const float* ffn_b2 = (const float*)d_in[17];
  float* out = (float*)d_out;

  char* ws = (char*)d_ws;
  size_t o = 0;
  float* local_out = (float*)(ws + o); o += (size_t)N_NODES * C_DIM * 4;  // 8 MB
  int* deg    = (int*)(ws + o); o += (N_NODES) * 4;
  int* off    = (int*)(ws + o); o += (N_NODES + 16) * 4;
  int* cursor = (int*)(ws + o); o += (N_NODES) * 4;
  int* csr    = (int*)(ws + o); o += (size_t)E_EDGES * 4;
  u16* xb   = (u16*)(ws + o); o += (size_t)N_NODES * C_DIM * 2;           // 4 MB
  u16* wbLQ = (u16*)(ws + o); o += (size_t)4 * C_DIM * C_DIM * 2;         // 2 MB
  u16* wbA  = (u16*)(ws + o); o += (size_t)C_DIM * C_DIM * 2;
  u16* wbO  = (u16*)(ws + o); o += (size_t)C_DIM * C_DIM * 2;
  u16* wbF1 = (u16*)(ws + o); o += (size_t)2 * C_DIM * C_DIM * 2;
  u16* wbF2 = (u16*)(ws + o); o += (size_t)2 * C_DIM * C_DIM * 2;
  u16* local_h   = (u16*)(ws + o); o += (size_t)N_NODES * C_DIM * 2;
  u16* qkvb      = (u16*)(ws + o); o += (size_t)N_NODES * 3 * C_DIM * 2;  // 12 MB
  u16* ctxb      = (u16*)(ws + o); o += (size_t)N_NODES * C_DIM * 2;
  u16* mixed     = (u16*)(ws + o); o += (size_t)N_NODES * C_DIM * 2;
  u16* hidden_bf = (u16*)(ws + o); o += (size_t)N_NODES * C_DIM * 2;      // 4 MB
  float* hidden_f = (float*)(ws + o); o += (size_t)N_NODES * C_DIM * 4;   // 8 MB
  u16* ff1       = (u16*)(ws + o); o += (size_t)N_NODES * 2 * C_DIM * 2;  // 8 MB
  // aliases (dead ranges reused):
  float* proj  = (float*)qkvb;       // qkv dead after attn; proj 8 MB <= 12 MB
  float* ff2   = (float*)local_out;  // local_out dead after mix-epilogue gemm
  u16*   vt    = xb;                 // xb dead after LQKV gemm; 4 MB
  // SPLITS=4 scratch (32.5 MB) goes past ff1 if workspace allows
  float* opart4 = (float*)(ws + o);
  float* lpart4 = (float*)(ws + o + (size_t)4 * N_NODES * C_DIM * 4);
  const size_t need4 = o + (size_t)4 * N_NODES * C_DIM * 4 + (size_t)4 * N_NODES * H_HEADS * 4;
  const bool use4 = (ws_size >= need4);
  // SPLITS=2 fallback: inside hidden_bf..ff1 region (16.25 MB <= 20 MB)
  float* opart2 = (float*)hidden_bf;
  float* lpart2 = opart2 + (size_t)2 * N_NODES * C_DIM;

  (void)hipMemsetAsync(deg, 0, N_NODES * 4, stream);

  // fp32 -> bf16 conversions (x + weights) + fused degree histogram
  CvtArgs ca;
  ca.src[0] = x;          ca.dst[0] = xb;   ca.n[0] = N_NODES * C_DIM;
  ca.src[1] = local_w;    ca.dst[1] = wbLQ;                  ca.n[1] = C_DIM * C_DIM;
  ca.src[2] = in_proj_w;  ca.dst[2] = wbLQ + C_DIM * C_DIM;  ca.n[2] = 3 * C_DIM * C_DIM;
  ca.src[3] = attn_out_w; ca.dst[3] = wbA;  ca.n[3] = C_DIM * C_DIM;
  ca.src[4] = output_w;   ca.dst[4] = wbO;  ca.n[4] = C_DIM * C_DIM;
  ca.src[5] = ffn_w1;     ca.dst[5] = wbF1; ca.n[5] = 2 * C_DIM * C_DIM;
  ca.src[6] = ffn_w2;     ca.dst[6] = wbF2; ca.n[6] = 2 * C_DIM * C_DIM;
  ca.ei = ei; ca.deg = deg;
  cvt_multi<<<dim3(N_NODES * C_DIM / 2048, 8), 256, 0, stream>>>(ca);

  // CSR build
  scan_kernel<<<1, 256, 0, stream>>>(deg, off, cursor);
  fill_kernel<<<E_EDGES / 256, 256, 0, stream>>>(ei, cursor, csr);

  // merged local+qkv GEMM: [local_h | qkvb] = xb @ [local_w; in_proj_w]^T
  gemm128<0><<<dim3(32, 16), 256, 0, stream>>>(xb, wbLQ, local_b, in_proj_b,
      local_h, qkvb, N_NODES, 4 * C_DIM, C_DIM);
  gather_kernel<<<N_NODES / 4, 256, 0, stream>>>(off, csr, local_h, local_out);

  // global branch
  vtrans_kernel<<<dim3(64, 8), 256, 0, stream>>>(qkvb, vt);   // xb dead now
  if (use4) {
    attn_kernel<4><<<dim3(32, 8, 4), 256, 0, stream>>>(qkvb, vt, opart4, lpart4);
    attn_combine<4><<<N_NODES * C_DIM / 2048, 256, 0, stream>>>(opart4, lpart4, ctxb);
  } else {
    attn_kernel<2><<<dim3(32, 8, 2), 256, 0, stream>>>(qkvb, vt, opart2, lpart2);
    attn_combine<2><<<N_NODES * C_DIM / 2048, 256, 0, stream>>>(opart2, lpart2, ctxb);
  }

  // mixed = 0.5*local_out + 0.5*(ctx @ attn_out_w^T + b)
  gemm_bt<3><<<dim3(64, 8), 256, 0, stream>>>(ctxb, wbA, attn_out_b, mixed,
      N_NODES, C_DIM, C_DIM, local_out);

  // proj = mixed @ output_w^T + b ; hidden = LN(x + proj)
  gemm_bt<1><<<dim3(64, 8), 256, 0, stream>>>(mixed, wbO, output_b, proj,
      N_NODES, C_DIM, C_DIM, nullptr);
  ln1_kernel<<<N_NODES / 4, 256, 0, stream>>>(x, proj, n1g, n1b, hidden_bf, hidden_f);

  // FFN
  gemm128<2><<<dim3(32, 8), 256, 0, stream>>>(hidden_bf, wbF1, ffn_b1, nullptr,
      ff1, nullptr, N_NODES, 2 * C_DIM, C_DIM);
  gemm_bt<1><<<dim3(64, 8), 256, 0, stream>>>(ff1, wbF2, ffn_b2, ff2,
      N_NODES, C_DIM, 2 * C_DIM, nullptr);
  ln2_kernel<<<N_NODES / 4, 256, 0, stream>>>(hidden_f, ff2, n2g, n2b, out);
}